// Round 1
// baseline (759.992 us; speedup 1.0000x reference)
//
#include <hip/hip_runtime.h>
#include <hip/hip_bf16.h>

#define NHEAD 4
#define NEG 0.2f

// ---------------- CSR build ----------------

__global__ __launch_bounds__(256) void hist_k(const int* __restrict__ dst,
                                              int* __restrict__ deg, int E) {
    int e = blockIdx.x * 256 + threadIdx.x;
    if (e < E) atomicAdd(&deg[dst[e]], 1);
}

__global__ __launch_bounds__(1024) void scan_k(const int* __restrict__ deg,
                                               int* __restrict__ rowptr,
                                               int* __restrict__ fill,
                                               int n, int total) {
    __shared__ int part[1024];
    int t = threadIdx.x;
    int C = (n + 1023) >> 10;
    int base = t * C;
    int sum = 0;
    for (int i = 0; i < C; ++i) {
        int idx = base + i;
        if (idx < n) sum += deg[idx];
    }
    part[t] = sum;
    __syncthreads();
    for (int off = 1; off < 1024; off <<= 1) {
        int v = (t >= off) ? part[t - off] : 0;
        __syncthreads();
        part[t] += v;
        __syncthreads();
    }
    int run = part[t] - sum;  // exclusive prefix
    for (int i = 0; i < C; ++i) {
        int idx = base + i;
        if (idx < n) {
            rowptr[idx] = run;
            fill[idx] = run;
            run += deg[idx];
        }
    }
    if (t == 0) rowptr[n] = total;
}

__global__ __launch_bounds__(256) void scatter_k(const int* __restrict__ src,
                                                 const int* __restrict__ dst,
                                                 const float* __restrict__ ew,
                                                 int* __restrict__ fill,
                                                 int* __restrict__ srcs,
                                                 float* __restrict__ wsrt, int E) {
    int e = blockIdx.x * 256 + threadIdx.x;
    if (e < E) {
        int d = dst[e];
        int p = atomicAdd(&fill[d], 1);
        srcs[p] = src[e];
        wsrt[p] = ew[e];
    }
}

// ---------------- GEMM: out[N,M] = X[N,K] @ W[K,M] + b ----------------
// 32 rows per block, 256 threads, CPT cols per thread (M = 256*CPT).

template <int K, int M, int CPT>
__global__ __launch_bounds__(256) void gemm_bias_k(const float* __restrict__ X,
                                                   const float* __restrict__ W,
                                                   const float* __restrict__ b,
                                                   float* __restrict__ out,
                                                   int nrows) {
    constexpr int ROWS = 32;
    __shared__ float xs[ROWS * K];
    int r0 = blockIdx.x * ROWS;

    for (int i = threadIdx.x; i < ROWS * K; i += 256) {
        int r = r0 + i / K;
        xs[i] = (r < nrows) ? X[(size_t)r0 * K + i] : 0.f;
    }
    __syncthreads();

    float acc[CPT][ROWS];
#pragma unroll
    for (int j = 0; j < CPT; ++j)
#pragma unroll
        for (int r = 0; r < ROWS; ++r) acc[j][r] = 0.f;

    int c0 = threadIdx.x;

    for (int k = 0; k < K; k += 4) {
        float w0[CPT], w1[CPT], w2[CPT], w3[CPT];
#pragma unroll
        for (int j = 0; j < CPT; ++j) {
            int c = c0 + j * 256;
            w0[j] = W[(size_t)(k + 0) * M + c];
            w1[j] = W[(size_t)(k + 1) * M + c];
            w2[j] = W[(size_t)(k + 2) * M + c];
            w3[j] = W[(size_t)(k + 3) * M + c];
        }
#pragma unroll
        for (int r = 0; r < ROWS; ++r) {
            float4 x4 = *(const float4*)&xs[r * K + k];
#pragma unroll
            for (int j = 0; j < CPT; ++j) {
                acc[j][r] += x4.x * w0[j] + x4.y * w1[j] + x4.z * w2[j] + x4.w * w3[j];
            }
        }
    }

#pragma unroll
    for (int j = 0; j < CPT; ++j) {
        int c = c0 + j * 256;
        float bias = b[c];
#pragma unroll
        for (int r = 0; r < ROWS; ++r) {
            int row = r0 + r;
            if (row < nrows) out[(size_t)row * M + c] = acc[j][r] + bias;
        }
    }
}

// ---------------- per-node attention scores: s[n,h] = dot(h[n,h,:], att[h,:]) ----------------

template <int D>
__global__ __launch_bounds__(256) void score_k(const float* __restrict__ hbuf,
                                               const float* __restrict__ att,
                                               float* __restrict__ s, int n) {
    int gt = blockIdx.x * 256 + threadIdx.x;
    int node = gt >> 6, lane = gt & 63;
    if (node >= n) return;
    const float* hp = hbuf + (size_t)node * (NHEAD * D);
    float sv0 = 0.f, sv1 = 0.f, sv2 = 0.f, sv3 = 0.f;
#pragma unroll
    for (int hh = 0; hh < NHEAD; ++hh) {
        float p = 0.f;
#pragma unroll
        for (int dd = 0; dd < D / 64; ++dd) {
            int d = dd * 64 + lane;
            p += hp[hh * D + d] * att[hh * D + d];
        }
#pragma unroll
        for (int off = 32; off; off >>= 1) p += __shfl_xor(p, off, 64);
        if (hh == 0) sv0 = p;
        if (hh == 1) sv1 = p;
        if (hh == 2) sv2 = p;
        if (hh == 3) sv3 = p;
    }
    if (lane == 0) {
        float4 v = make_float4(sv0, sv1, sv2, sv3);
        *(float4*)&s[(size_t)node * NHEAD] = v;
    }
}

// ---------------- per-node aggregation over incoming edges ----------------
// one wave (64 lanes) per node; lane = feature dim (D/64 dims per lane)

template <int D, bool RELU>
__global__ __launch_bounds__(256) void aggr_k(const int* __restrict__ rowptr,
                                              const int* __restrict__ srcs,
                                              const float* __restrict__ wsrt,
                                              const float* __restrict__ s,
                                              const float* __restrict__ hbuf,
                                              float* __restrict__ out, int n) {
    int gt = blockIdx.x * 256 + threadIdx.x;
    int node = gt >> 6, lane = gt & 63;
    if (node >= n) return;
    int beg = rowptr[node], end = rowptr[node + 1];

    float acc[D / 64];
#pragma unroll
    for (int dd = 0; dd < D / 64; ++dd) acc[dd] = 0.f;

    for (int e = beg; e < end; ++e) {
        int sn = srcs[e];
        float w = wsrt[e];
        const float* sp = s + (size_t)sn * NHEAD;
        float a0 = sp[0], a1 = sp[1], a2 = sp[2], a3 = sp[3];
        a0 = (a0 > 0.f ? a0 : NEG * a0) * w;
        a1 = (a1 > 0.f ? a1 : NEG * a1) * w;
        a2 = (a2 > 0.f ? a2 : NEG * a2) * w;
        a3 = (a3 > 0.f ? a3 : NEG * a3) * w;
        float m = fmaxf(fmaxf(a0, a1), fmaxf(a2, a3));
        float e0 = __expf(a0 - m), e1 = __expf(a1 - m);
        float e2 = __expf(a2 - m), e3 = __expf(a3 - m);
        float inv = 1.f / (e0 + e1 + e2 + e3);
        e0 *= inv; e1 *= inv; e2 *= inv; e3 *= inv;

        const float* hp = hbuf + (size_t)sn * (NHEAD * D);
#pragma unroll
        for (int dd = 0; dd < D / 64; ++dd) {
            int d = dd * 64 + lane;
            acc[dd] += e0 * hp[0 * D + d] + e1 * hp[1 * D + d] +
                       e2 * hp[2 * D + d] + e3 * hp[3 * D + d];
        }
    }

#pragma unroll
    for (int dd = 0; dd < D / 64; ++dd) {
        float v = acc[dd] * 0.25f;
        if (RELU) v = fmaxf(v, 0.f);
        out[(size_t)node * D + dd * 64 + lane] = v;
    }
}

// ---------------- launch ----------------

extern "C" void kernel_launch(void* const* d_in, const int* in_sizes, int n_in,
                              void* d_out, int out_size, void* d_ws, size_t ws_size,
                              hipStream_t stream) {
    const float* x    = (const float*)d_in[0];
    const int*   ei   = (const int*)d_in[1];
    const float* ew   = (const float*)d_in[2];
    const float* W1   = (const float*)d_in[3];
    const float* b1   = (const float*)d_in[4];
    const float* att1 = (const float*)d_in[5];
    const float* W2   = (const float*)d_in[6];
    const float* b2   = (const float*)d_in[7];
    const float* att2 = (const float*)d_in[8];
    const float* W3   = (const float*)d_in[9];
    const float* b3   = (const float*)d_in[10];
    const float* att3 = (const float*)d_in[11];

    const int N = in_sizes[0] / 128;   // x is [N,128]
    const int E = in_sizes[2];         // edge_weight is [E]
    const int* src = ei;
    const int* dst = ei + E;

    char* wp = (char*)d_ws;
    auto alloc = [&](size_t bytes) -> void* {
        void* p = (void*)wp;
        wp += (bytes + 511) & ~(size_t)511;
        return p;
    };
    int*   deg    = (int*)alloc((size_t)N * 4);
    int*   rowptr = (int*)alloc((size_t)(N + 1) * 4);
    int*   fill   = (int*)alloc((size_t)N * 4);
    int*   srcs   = (int*)alloc((size_t)E * 4);
    float* wsrt   = (float*)alloc((size_t)E * 4);
    float* h      = (float*)alloc((size_t)N * 512 * 4);  // max H*OUT = 512 cols
    float* s      = (float*)alloc((size_t)N * NHEAD * 4);
    float* a1     = (float*)alloc((size_t)N * 64 * 4);
    float* a2     = (float*)alloc((size_t)N * 64 * 4);

    // --- CSR build (shared by all 3 layers) ---
    hipMemsetAsync(deg, 0, (size_t)N * 4, stream);
    int ge = (E + 255) / 256;
    hist_k<<<ge, 256, 0, stream>>>(dst, deg, E);
    scan_k<<<1, 1024, 0, stream>>>(deg, rowptr, fill, N, E);
    scatter_k<<<ge, 256, 0, stream>>>(src, dst, ew, fill, srcs, wsrt, E);

    int gb = (N + 31) / 32;
    int ga = (N * 64 + 255) / 256;

    // --- layer 1: IN=128 -> H*64 ---
    gemm_bias_k<128, 256, 1><<<gb, 256, 0, stream>>>(x, W1, b1, h, N);
    score_k<64><<<ga, 256, 0, stream>>>(h, att1, s, N);
    aggr_k<64, true><<<ga, 256, 0, stream>>>(rowptr, srcs, wsrt, s, h, a1, N);

    // --- layer 2: 64 -> H*64 ---
    gemm_bias_k<64, 256, 1><<<gb, 256, 0, stream>>>(a1, W2, b2, h, N);
    score_k<64><<<ga, 256, 0, stream>>>(h, att2, s, N);
    aggr_k<64, true><<<ga, 256, 0, stream>>>(rowptr, srcs, wsrt, s, h, a2, N);

    // --- layer 3: 64 -> H*128 ---
    gemm_bias_k<64, 512, 2><<<gb, 256, 0, stream>>>(a2, W3, b3, h, N);
    score_k<128><<<ga, 256, 0, stream>>>(h, att3, s, N);
    aggr_k<128, false><<<ga, 256, 0, stream>>>(rowptr, srcs, wsrt, s, h, (float*)d_out, N);
}

// Round 2
// 636.170 us; speedup vs baseline: 1.1946x; 1.1946x over previous
//
#include <hip/hip_runtime.h>
#include <hip/hip_bf16.h>

#define NHEAD 4
#define NEG 0.2f

__device__ __forceinline__ float blo(unsigned u) { return __uint_as_float(u << 16); }
__device__ __forceinline__ float bhi(unsigned u) { return __uint_as_float(u & 0xffff0000u); }

// ---------------- CSR build ----------------

__global__ __launch_bounds__(256) void hist_k(const int* __restrict__ dst,
                                              int* __restrict__ deg, int E) {
    int e = blockIdx.x * 256 + threadIdx.x;
    if (e < E) atomicAdd(&deg[dst[e]], 1);
}

__global__ __launch_bounds__(1024) void scan_k(const int* __restrict__ deg,
                                               int* __restrict__ rowptr,
                                               int* __restrict__ fill,
                                               int n, int total) {
    __shared__ int part[1024];
    int t = threadIdx.x;
    int C = (n + 1023) >> 10;
    int base = t * C;
    int sum = 0;
    for (int i = 0; i < C; ++i) {
        int idx = base + i;
        if (idx < n) sum += deg[idx];
    }
    part[t] = sum;
    __syncthreads();
    for (int off = 1; off < 1024; off <<= 1) {
        int v = (t >= off) ? part[t - off] : 0;
        __syncthreads();
        part[t] += v;
        __syncthreads();
    }
    int run = part[t] - sum;  // exclusive prefix
    for (int i = 0; i < C; ++i) {
        int idx = base + i;
        if (idx < n) {
            rowptr[idx] = run;
            fill[idx] = run;
            run += deg[idx];
        }
    }
    if (t == 0) rowptr[n] = total;
}

__global__ __launch_bounds__(256) void scatter_k(const int* __restrict__ src,
                                                 const int* __restrict__ dst,
                                                 const float* __restrict__ ew,
                                                 int* __restrict__ fill,
                                                 int* __restrict__ srcs,
                                                 float* __restrict__ wsrt, int E) {
    int e = blockIdx.x * 256 + threadIdx.x;
    if (e < E) {
        int d = dst[e];
        int p = atomicAdd(&fill[d], 1);
        srcs[p] = src[e];
        wsrt[p] = ew[e];
    }
}

// ---------------- GEMM: h_bf16t[N, d, h] = X[N,K] @ W[K,M] + b ----------------
// 32 rows/block, 256 threads = 128 cols x 2 row-halves; CPT = M/128 cols/thread.
// Output stored transposed-per-node as bf16: out[node*(4*D) + d*4 + head].

template <int K, int M, int D>
__global__ __launch_bounds__(256) void gemm_bias_bf16t_k(const float* __restrict__ X,
                                                         const float* __restrict__ W,
                                                         const float* __restrict__ b,
                                                         __hip_bfloat16* __restrict__ out,
                                                         int nrows) {
    constexpr int CPT = M / 128;
    constexpr int RPT = 16;
    __shared__ float xs[32 * K];
    int r0 = blockIdx.x * 32;

    for (int i = threadIdx.x; i < 32 * K; i += 256) {
        int r = i / K;
        xs[i] = (r0 + r < nrows) ? X[(size_t)r0 * K + i] : 0.f;
    }
    __syncthreads();

    int c0 = threadIdx.x & 127;
    int rbase = (threadIdx.x >> 7) * RPT;

    float acc[CPT][RPT];
#pragma unroll
    for (int j = 0; j < CPT; ++j)
#pragma unroll
        for (int r = 0; r < RPT; ++r) acc[j][r] = 0.f;

    for (int k = 0; k < K; k += 4) {
        float w[4][CPT];
#pragma unroll
        for (int kk = 0; kk < 4; ++kk)
#pragma unroll
            for (int j = 0; j < CPT; ++j)
                w[kk][j] = W[(size_t)(k + kk) * M + c0 + j * 128];
#pragma unroll
        for (int r = 0; r < RPT; ++r) {
            float4 x4 = *(const float4*)&xs[(rbase + r) * K + k];
#pragma unroll
            for (int j = 0; j < CPT; ++j) {
                acc[j][r] += x4.x * w[0][j] + x4.y * w[1][j] +
                             x4.z * w[2][j] + x4.w * w[3][j];
            }
        }
    }

#pragma unroll
    for (int j = 0; j < CPT; ++j) {
        int c = c0 + j * 128;
        float bias = b[c];
        int hh = c / D, d = c % D;
#pragma unroll
        for (int r = 0; r < RPT; ++r) {
            int row = r0 + rbase + r;
            if (row < nrows)
                out[(size_t)row * (4 * D) + d * 4 + hh] = __float2bfloat16(acc[j][r] + bias);
        }
    }
}

// ---------------- per-node scores from transposed bf16 h ----------------

template <int D>
__global__ __launch_bounds__(256) void score_t_k(const __hip_bfloat16* __restrict__ h,
                                                 const float* __restrict__ att,
                                                 float* __restrict__ s, int n) {
    int gt = blockIdx.x * 256 + threadIdx.x;
    int node = gt >> 6, lane = gt & 63;
    if (node >= n) return;
    const uint2* hp = (const uint2*)(h + (size_t)node * (4 * D));
    float p0 = 0.f, p1 = 0.f, p2 = 0.f, p3 = 0.f;
#pragma unroll
    for (int dd = 0; dd < D / 64; ++dd) {
        int d = dd * 64 + lane;
        uint2 u = hp[d];
        p0 += blo(u.x) * att[0 * D + d];
        p1 += bhi(u.x) * att[1 * D + d];
        p2 += blo(u.y) * att[2 * D + d];
        p3 += bhi(u.y) * att[3 * D + d];
    }
#pragma unroll
    for (int off = 32; off; off >>= 1) {
        p0 += __shfl_xor(p0, off, 64);
        p1 += __shfl_xor(p1, off, 64);
        p2 += __shfl_xor(p2, off, 64);
        p3 += __shfl_xor(p3, off, 64);
    }
    if (lane == 0) {
        *(float4*)&s[(size_t)node * NHEAD] = make_float4(p0, p1, p2, p3);
    }
}

// ---------------- per-edge alpha: leaky, *w, softmax over heads, /H ----------------

__global__ __launch_bounds__(256) void alpha_k(const int* __restrict__ srcs,
                                               const float* __restrict__ wsrt,
                                               const float* __restrict__ s,
                                               float* __restrict__ alpha, int E) {
    int e = blockIdx.x * 256 + threadIdx.x;
    if (e >= E) return;
    int sn = srcs[e];
    float w = wsrt[e];
    float4 sv = *(const float4*)&s[(size_t)sn * NHEAD];
    float a0 = (sv.x > 0.f ? sv.x : NEG * sv.x) * w;
    float a1 = (sv.y > 0.f ? sv.y : NEG * sv.y) * w;
    float a2 = (sv.z > 0.f ? sv.z : NEG * sv.z) * w;
    float a3 = (sv.w > 0.f ? sv.w : NEG * sv.w) * w;
    float m = fmaxf(fmaxf(a0, a1), fmaxf(a2, a3));
    float e0 = __expf(a0 - m), e1 = __expf(a1 - m);
    float e2 = __expf(a2 - m), e3 = __expf(a3 - m);
    float inv = 0.25f / (e0 + e1 + e2 + e3);  // fold mean-over-heads
    *(float4*)&alpha[(size_t)e * 4] = make_float4(e0 * inv, e1 * inv, e2 * inv, e3 * inv);
}

// ---------------- per-node aggregation (wave per node, lane = dim) ----------------

template <int D, bool RELU>
__global__ __launch_bounds__(256) void aggr_t_k(const int* __restrict__ rowptr,
                                                const int* __restrict__ srcs,
                                                const float* __restrict__ alpha,
                                                const __hip_bfloat16* __restrict__ h,
                                                float* __restrict__ out, int n) {
    int gt = blockIdx.x * 256 + threadIdx.x;
    int node = gt >> 6, lane = gt & 63;
    if (node >= n) return;
    int beg = rowptr[node], end = rowptr[node + 1];

    if (D == 64) {
        const uint2* hp = (const uint2*)h;  // node stride = D uint2
        float acc = 0.f, accB = 0.f;
        int e = beg;
        for (; e + 1 < end; e += 2) {
            int snA = srcs[e], snB = srcs[e + 1];
            float4 alA = *(const float4*)&alpha[(size_t)e * 4];
            float4 alB = *(const float4*)&alpha[(size_t)(e + 1) * 4];
            uint2 uA = hp[(size_t)snA * 64 + lane];
            uint2 uB = hp[(size_t)snB * 64 + lane];
            acc  += alA.x * blo(uA.x) + alA.y * bhi(uA.x) + alA.z * blo(uA.y) + alA.w * bhi(uA.y);
            accB += alB.x * blo(uB.x) + alB.y * bhi(uB.x) + alB.z * blo(uB.y) + alB.w * bhi(uB.y);
        }
        if (e < end) {
            int sn = srcs[e];
            float4 al = *(const float4*)&alpha[(size_t)e * 4];
            uint2 u = hp[(size_t)sn * 64 + lane];
            acc += al.x * blo(u.x) + al.y * bhi(u.x) + al.z * blo(u.y) + al.w * bhi(u.y);
        }
        float v = acc + accB;
        if (RELU) v = fmaxf(v, 0.f);
        out[(size_t)node * 64 + lane] = v;
    } else {
        // D == 128: lane owns dims 2*lane, 2*lane+1; 16B load covers both (4 heads each)
        const uint4* hp = (const uint4*)h;  // node stride = 64 uint4
        float acc0 = 0.f, acc1 = 0.f;
        for (int e = beg; e < end; ++e) {
            int sn = srcs[e];
            float4 al = *(const float4*)&alpha[(size_t)e * 4];
            uint4 u = hp[(size_t)sn * 64 + lane];
            acc0 += al.x * blo(u.x) + al.y * bhi(u.x) + al.z * blo(u.y) + al.w * bhi(u.y);
            acc1 += al.x * blo(u.z) + al.y * bhi(u.z) + al.z * blo(u.w) + al.w * bhi(u.w);
        }
        float2 v = make_float2(acc0, acc1);
        if (RELU) { v.x = fmaxf(v.x, 0.f); v.y = fmaxf(v.y, 0.f); }
        *(float2*)&out[(size_t)node * 128 + lane * 2] = v;
    }
}

// ---------------- launch ----------------

extern "C" void kernel_launch(void* const* d_in, const int* in_sizes, int n_in,
                              void* d_out, int out_size, void* d_ws, size_t ws_size,
                              hipStream_t stream) {
    const float* x    = (const float*)d_in[0];
    const int*   ei   = (const int*)d_in[1];
    const float* ew   = (const float*)d_in[2];
    const float* W1   = (const float*)d_in[3];
    const float* b1   = (const float*)d_in[4];
    const float* att1 = (const float*)d_in[5];
    const float* W2   = (const float*)d_in[6];
    const float* b2   = (const float*)d_in[7];
    const float* att2 = (const float*)d_in[8];
    const float* W3   = (const float*)d_in[9];
    const float* b3   = (const float*)d_in[10];
    const float* att3 = (const float*)d_in[11];

    const int N = in_sizes[0] / 128;
    const int E = in_sizes[2];
    const int* src = ei;
    const int* dst = ei + E;

    char* wp = (char*)d_ws;
    auto alloc = [&](size_t bytes) -> void* {
        void* p = (void*)wp;
        wp += (bytes + 511) & ~(size_t)511;
        return p;
    };
    int*   deg    = (int*)alloc((size_t)N * 4);
    int*   rowptr = (int*)alloc((size_t)(N + 1) * 4);
    int*   fill   = (int*)alloc((size_t)N * 4);
    int*   srcs   = (int*)alloc((size_t)E * 4);
    float* wsrt   = (float*)alloc((size_t)E * 4);
    __hip_bfloat16* h = (__hip_bfloat16*)alloc((size_t)N * 512 * 2);  // max H*OUT bf16
    float* s      = (float*)alloc((size_t)N * NHEAD * 4);
    float* alpha  = (float*)alloc((size_t)E * 4 * 4);
    float* a1     = (float*)alloc((size_t)N * 64 * 4);
    float* a2     = (float*)alloc((size_t)N * 64 * 4);

    // --- CSR build (shared by all 3 layers) ---
    hipMemsetAsync(deg, 0, (size_t)N * 4, stream);
    int ge = (E + 255) / 256;
    hist_k<<<ge, 256, 0, stream>>>(dst, deg, E);
    scan_k<<<1, 1024, 0, stream>>>(deg, rowptr, fill, N, E);
    scatter_k<<<ge, 256, 0, stream>>>(src, dst, ew, fill, srcs, wsrt, E);

    int gb = (N + 31) / 32;
    int ga = (N * 64 + 255) / 256;

    // --- layer 1: IN=128 -> H*64 ---
    gemm_bias_bf16t_k<128, 256, 64><<<gb, 256, 0, stream>>>(x, W1, b1, h, N);
    score_t_k<64><<<ga, 256, 0, stream>>>(h, att1, s, N);
    alpha_k<<<ge, 256, 0, stream>>>(srcs, wsrt, s, alpha, E);
    aggr_t_k<64, true><<<ga, 256, 0, stream>>>(rowptr, srcs, alpha, h, a1, N);

    // --- layer 2: 64 -> H*64 ---
    gemm_bias_bf16t_k<64, 256, 64><<<gb, 256, 0, stream>>>(a1, W2, b2, h, N);
    score_t_k<64><<<ga, 256, 0, stream>>>(h, att2, s, N);
    alpha_k<<<ge, 256, 0, stream>>>(srcs, wsrt, s, alpha, E);
    aggr_t_k<64, true><<<ga, 256, 0, stream>>>(rowptr, srcs, alpha, h, a2, N);

    // --- layer 3: 64 -> H*128 ---
    gemm_bias_bf16t_k<64, 512, 128><<<gb, 256, 0, stream>>>(a2, W3, b3, h, N);
    score_t_k<128><<<ga, 256, 0, stream>>>(h, att3, s, N);
    alpha_k<<<ge, 256, 0, stream>>>(srcs, wsrt, s, alpha, E);
    aggr_t_k<128, false><<<ga, 256, 0, stream>>>(rowptr, srcs, alpha, h, (float*)d_out, N);
}

// Round 3
// 526.936 us; speedup vs baseline: 1.4423x; 1.2073x over previous
//
#include <hip/hip_runtime.h>
#include <hip/hip_bf16.h>

#define NHEAD 4
#define NEG 0.2f

__device__ __forceinline__ float blo(unsigned u) { return __uint_as_float(u << 16); }
__device__ __forceinline__ float bhi(unsigned u) { return __uint_as_float(u & 0xffff0000u); }

// ---------------- CSR build ----------------

__global__ __launch_bounds__(256) void hist_k(const int* __restrict__ dst,
                                              int* __restrict__ deg, int E) {
    int e = blockIdx.x * 256 + threadIdx.x;
    if (e < E) atomicAdd(&deg[dst[e]], 1);
}

// Phase A: per-block (2048 elems) totals
__global__ __launch_bounds__(256) void partial_k(const int* __restrict__ deg,
                                                 int* __restrict__ bsum, int n) {
    int t = threadIdx.x;
    int base = blockIdx.x * 2048 + t * 8;
    int s = 0;
#pragma unroll
    for (int i = 0; i < 8; ++i) {
        int idx = base + i;
        if (idx < n) s += deg[idx];
    }
#pragma unroll
    for (int off = 32; off; off >>= 1) s += __shfl_down(s, off, 64);
    __shared__ int ws[4];
    if ((t & 63) == 0) ws[t >> 6] = s;
    __syncthreads();
    if (t == 0) bsum[blockIdx.x] = ws[0] + ws[1] + ws[2] + ws[3];
}

// Phase B: exclusive scan of block sums (nb <= 256), one block
__global__ __launch_bounds__(256) void bscan_k(const int* __restrict__ bsum,
                                               int* __restrict__ boff, int nb) {
    __shared__ int sh[256];
    int t = threadIdx.x;
    int v = (t < nb) ? bsum[t] : 0;
    sh[t] = v;
    __syncthreads();
    for (int off = 1; off < 256; off <<= 1) {
        int u = (t >= off) ? sh[t - off] : 0;
        __syncthreads();
        sh[t] += u;
        __syncthreads();
    }
    if (t < nb) boff[t] = sh[t] - v;  // exclusive
}

// Phase C: block-local rescan + offset, write rowptr & fill
__global__ __launch_bounds__(256) void rescan_k(const int* __restrict__ deg,
                                                const int* __restrict__ boff,
                                                int* __restrict__ rowptr,
                                                int* __restrict__ fill,
                                                int n, int total) {
    __shared__ int ts[256];
    int t = threadIdx.x;
    int base = blockIdx.x * 2048 + t * 8;
    int v[8];
    int s = 0;
#pragma unroll
    for (int i = 0; i < 8; ++i) {
        int idx = base + i;
        v[i] = (idx < n) ? deg[idx] : 0;
        s += v[i];
    }
    ts[t] = s;
    __syncthreads();
    for (int off = 1; off < 256; off <<= 1) {
        int u = (t >= off) ? ts[t - off] : 0;
        __syncthreads();
        ts[t] += u;
        __syncthreads();
    }
    int run = boff[blockIdx.x] + ts[t] - s;  // exclusive prefix for this thread
#pragma unroll
    for (int i = 0; i < 8; ++i) {
        int idx = base + i;
        if (idx < n) {
            rowptr[idx] = run;
            fill[idx] = run;
            run += v[i];
        }
    }
    if (blockIdx.x == 0 && t == 0) rowptr[n] = total;
}

__global__ __launch_bounds__(256) void scatter_k(const int* __restrict__ src,
                                                 const int* __restrict__ dst,
                                                 const float* __restrict__ ew,
                                                 int* __restrict__ fill,
                                                 int* __restrict__ srcs,
                                                 float* __restrict__ wsrt, int E) {
    int e = blockIdx.x * 256 + threadIdx.x;
    if (e < E) {
        int d = dst[e];
        int p = atomicAdd(&fill[d], 1);
        srcs[p] = src[e];
        wsrt[p] = ew[e];
    }
}

// ---------------- GEMM: h_bf16t[N, d, h] = X[N,K] @ W[K,M] + b ----------------
// 32 rows/block, 256 threads = 128 cols x 2 row-halves; CPT = M/128 cols/thread.
// Output stored transposed-per-node as bf16: out[node*(4*D) + d*4 + head].

template <int K, int M, int D>
__global__ __launch_bounds__(256) void gemm_bias_bf16t_k(const float* __restrict__ X,
                                                         const float* __restrict__ W,
                                                         const float* __restrict__ b,
                                                         __hip_bfloat16* __restrict__ out,
                                                         int nrows) {
    constexpr int CPT = M / 128;
    constexpr int RPT = 16;
    __shared__ float xs[32 * K];
    int r0 = blockIdx.x * 32;

    for (int i = threadIdx.x; i < 32 * K; i += 256) {
        int r = i / K;
        xs[i] = (r0 + r < nrows) ? X[(size_t)r0 * K + i] : 0.f;
    }
    __syncthreads();

    int c0 = threadIdx.x & 127;
    int rbase = (threadIdx.x >> 7) * RPT;

    float acc[CPT][RPT];
#pragma unroll
    for (int j = 0; j < CPT; ++j)
#pragma unroll
        for (int r = 0; r < RPT; ++r) acc[j][r] = 0.f;

    for (int k = 0; k < K; k += 4) {
        float w[4][CPT];
#pragma unroll
        for (int kk = 0; kk < 4; ++kk)
#pragma unroll
            for (int j = 0; j < CPT; ++j)
                w[kk][j] = W[(size_t)(k + kk) * M + c0 + j * 128];
#pragma unroll
        for (int r = 0; r < RPT; ++r) {
            float4 x4 = *(const float4*)&xs[(rbase + r) * K + k];
#pragma unroll
            for (int j = 0; j < CPT; ++j) {
                acc[j][r] += x4.x * w[0][j] + x4.y * w[1][j] +
                             x4.z * w[2][j] + x4.w * w[3][j];
            }
        }
    }

#pragma unroll
    for (int j = 0; j < CPT; ++j) {
        int c = c0 + j * 128;
        float bias = b[c];
        int hh = c / D, d = c % D;
#pragma unroll
        for (int r = 0; r < RPT; ++r) {
            int row = r0 + rbase + r;
            if (row < nrows)
                out[(size_t)row * (4 * D) + d * 4 + hh] = __float2bfloat16(acc[j][r] + bias);
        }
    }
}

// ---------------- per-node scores from transposed bf16 h ----------------

template <int D>
__global__ __launch_bounds__(256) void score_t_k(const __hip_bfloat16* __restrict__ h,
                                                 const float* __restrict__ att,
                                                 float* __restrict__ s, int n) {
    int gt = blockIdx.x * 256 + threadIdx.x;
    int node = gt >> 6, lane = gt & 63;
    if (node >= n) return;
    const uint2* hp = (const uint2*)(h + (size_t)node * (4 * D));
    float p0 = 0.f, p1 = 0.f, p2 = 0.f, p3 = 0.f;
#pragma unroll
    for (int dd = 0; dd < D / 64; ++dd) {
        int d = dd * 64 + lane;
        uint2 u = hp[d];
        p0 += blo(u.x) * att[0 * D + d];
        p1 += bhi(u.x) * att[1 * D + d];
        p2 += blo(u.y) * att[2 * D + d];
        p3 += bhi(u.y) * att[3 * D + d];
    }
#pragma unroll
    for (int off = 32; off; off >>= 1) {
        p0 += __shfl_xor(p0, off, 64);
        p1 += __shfl_xor(p1, off, 64);
        p2 += __shfl_xor(p2, off, 64);
        p3 += __shfl_xor(p3, off, 64);
    }
    if (lane == 0) {
        *(float4*)&s[(size_t)node * NHEAD] = make_float4(p0, p1, p2, p3);
    }
}

// ---------------- per-edge alpha: leaky, *w, softmax over heads, /H ----------------

__global__ __launch_bounds__(256) void alpha_k(const int* __restrict__ srcs,
                                               const float* __restrict__ wsrt,
                                               const float* __restrict__ s,
                                               float* __restrict__ alpha, int E) {
    int e = blockIdx.x * 256 + threadIdx.x;
    if (e >= E) return;
    int sn = srcs[e];
    float w = wsrt[e];
    float4 sv = *(const float4*)&s[(size_t)sn * NHEAD];
    float a0 = (sv.x > 0.f ? sv.x : NEG * sv.x) * w;
    float a1 = (sv.y > 0.f ? sv.y : NEG * sv.y) * w;
    float a2 = (sv.z > 0.f ? sv.z : NEG * sv.z) * w;
    float a3 = (sv.w > 0.f ? sv.w : NEG * sv.w) * w;
    float m = fmaxf(fmaxf(a0, a1), fmaxf(a2, a3));
    float e0 = __expf(a0 - m), e1 = __expf(a1 - m);
    float e2 = __expf(a2 - m), e3 = __expf(a3 - m);
    float inv = 0.25f / (e0 + e1 + e2 + e3);  // fold mean-over-heads
    *(float4*)&alpha[(size_t)e * 4] = make_float4(e0 * inv, e1 * inv, e2 * inv, e3 * inv);
}

// ---------------- per-node aggregation (wave per node, lane = dim) ----------------

template <int D, bool RELU>
__global__ __launch_bounds__(256) void aggr_t_k(const int* __restrict__ rowptr,
                                                const int* __restrict__ srcs,
                                                const float* __restrict__ alpha,
                                                const __hip_bfloat16* __restrict__ h,
                                                float* __restrict__ out, int n) {
    int gt = blockIdx.x * 256 + threadIdx.x;
    int node = gt >> 6, lane = gt & 63;
    if (node >= n) return;
    int beg = rowptr[node], end = rowptr[node + 1];

    if (D == 64) {
        const uint2* hp = (const uint2*)h;  // node stride = D uint2
        float acc = 0.f, accB = 0.f;
        int e = beg;
        for (; e + 1 < end; e += 2) {
            int snA = srcs[e], snB = srcs[e + 1];
            float4 alA = *(const float4*)&alpha[(size_t)e * 4];
            float4 alB = *(const float4*)&alpha[(size_t)(e + 1) * 4];
            uint2 uA = hp[(size_t)snA * 64 + lane];
            uint2 uB = hp[(size_t)snB * 64 + lane];
            acc  += alA.x * blo(uA.x) + alA.y * bhi(uA.x) + alA.z * blo(uA.y) + alA.w * bhi(uA.y);
            accB += alB.x * blo(uB.x) + alB.y * bhi(uB.x) + alB.z * blo(uB.y) + alB.w * bhi(uB.y);
        }
        if (e < end) {
            int sn = srcs[e];
            float4 al = *(const float4*)&alpha[(size_t)e * 4];
            uint2 u = hp[(size_t)sn * 64 + lane];
            acc += al.x * blo(u.x) + al.y * bhi(u.x) + al.z * blo(u.y) + al.w * bhi(u.y);
        }
        float v = acc + accB;
        if (RELU) v = fmaxf(v, 0.f);
        out[(size_t)node * 64 + lane] = v;
    } else {
        // D == 128: lane owns dims 2*lane, 2*lane+1; 16B load covers both (4 heads each)
        const uint4* hp = (const uint4*)h;  // node stride = 64 uint4
        float acc0 = 0.f, acc1 = 0.f;
        for (int e = beg; e < end; ++e) {
            int sn = srcs[e];
            float4 al = *(const float4*)&alpha[(size_t)e * 4];
            uint4 u = hp[(size_t)sn * 64 + lane];
            acc0 += al.x * blo(u.x) + al.y * bhi(u.x) + al.z * blo(u.y) + al.w * bhi(u.y);
            acc1 += al.x * blo(u.z) + al.y * bhi(u.z) + al.z * blo(u.w) + al.w * bhi(u.w);
        }
        float2 v = make_float2(acc0, acc1);
        if (RELU) { v.x = fmaxf(v.x, 0.f); v.y = fmaxf(v.y, 0.f); }
        *(float2*)&out[(size_t)node * 128 + lane * 2] = v;
    }
}

// ---------------- launch ----------------

extern "C" void kernel_launch(void* const* d_in, const int* in_sizes, int n_in,
                              void* d_out, int out_size, void* d_ws, size_t ws_size,
                              hipStream_t stream) {
    const float* x    = (const float*)d_in[0];
    const int*   ei   = (const int*)d_in[1];
    const float* ew   = (const float*)d_in[2];
    const float* W1   = (const float*)d_in[3];
    const float* b1   = (const float*)d_in[4];
    const float* att1 = (const float*)d_in[5];
    const float* W2   = (const float*)d_in[6];
    const float* b2   = (const float*)d_in[7];
    const float* att2 = (const float*)d_in[8];
    const float* W3   = (const float*)d_in[9];
    const float* b3   = (const float*)d_in[10];
    const float* att3 = (const float*)d_in[11];

    const int N = in_sizes[0] / 128;
    const int E = in_sizes[2];
    const int* src = ei;
    const int* dst = ei + E;

    char* wp = (char*)d_ws;
    auto alloc = [&](size_t bytes) -> void* {
        void* p = (void*)wp;
        wp += (bytes + 511) & ~(size_t)511;
        return p;
    };
    int*   deg    = (int*)alloc((size_t)N * 4);
    int*   rowptr = (int*)alloc((size_t)(N + 1) * 4);
    int*   fill   = (int*)alloc((size_t)N * 4);
    int*   bsum   = (int*)alloc(256 * 4);
    int*   boff   = (int*)alloc(256 * 4);
    int*   srcs   = (int*)alloc((size_t)E * 4);
    float* wsrt   = (float*)alloc((size_t)E * 4);
    __hip_bfloat16* h = (__hip_bfloat16*)alloc((size_t)N * 512 * 2);  // max H*OUT bf16
    float* s      = (float*)alloc((size_t)N * NHEAD * 4);
    float* alpha  = (float*)alloc((size_t)E * 4 * 4);
    float* a1     = (float*)alloc((size_t)N * 64 * 4);
    float* a2     = (float*)alloc((size_t)N * 64 * 4);

    // --- CSR build (shared by all 3 layers) ---
    hipMemsetAsync(deg, 0, (size_t)N * 4, stream);
    int ge = (E + 255) / 256;
    int nb = (N + 2047) / 2048;  // scan blocks (<=256 supported)
    hist_k<<<ge, 256, 0, stream>>>(dst, deg, E);
    partial_k<<<nb, 256, 0, stream>>>(deg, bsum, N);
    bscan_k<<<1, 256, 0, stream>>>(bsum, boff, nb);
    rescan_k<<<nb, 256, 0, stream>>>(deg, boff, rowptr, fill, N, E);
    scatter_k<<<ge, 256, 0, stream>>>(src, dst, ew, fill, srcs, wsrt, E);

    int gb = (N + 31) / 32;
    int ga = (N * 64 + 255) / 256;

    // --- layer 1: IN=128 -> H*64 ---
    gemm_bias_bf16t_k<128, 256, 64><<<gb, 256, 0, stream>>>(x, W1, b1, h, N);
    score_t_k<64><<<ga, 256, 0, stream>>>(h, att1, s, N);
    alpha_k<<<ge, 256, 0, stream>>>(srcs, wsrt, s, alpha, E);
    aggr_t_k<64, true><<<ga, 256, 0, stream>>>(rowptr, srcs, alpha, h, a1, N);

    // --- layer 2: 64 -> H*64 ---
    gemm_bias_bf16t_k<64, 256, 64><<<gb, 256, 0, stream>>>(a1, W2, b2, h, N);
    score_t_k<64><<<ga, 256, 0, stream>>>(h, att2, s, N);
    alpha_k<<<ge, 256, 0, stream>>>(srcs, wsrt, s, alpha, E);
    aggr_t_k<64, true><<<ga, 256, 0, stream>>>(rowptr, srcs, alpha, h, a2, N);

    // --- layer 3: 64 -> H*128 ---
    gemm_bias_bf16t_k<64, 512, 128><<<gb, 256, 0, stream>>>(a2, W3, b3, h, N);
    score_t_k<128><<<ga, 256, 0, stream>>>(h, att3, s, N);
    alpha_k<<<ge, 256, 0, stream>>>(srcs, wsrt, s, alpha, E);
    aggr_t_k<128, false><<<ga, 256, 0, stream>>>(rowptr, srcs, alpha, h, (float*)d_out, N);
}

// Round 4
// 398.161 us; speedup vs baseline: 1.9088x; 1.3234x over previous
//
#include <hip/hip_runtime.h>
#include <hip/hip_bf16.h>

#define NHEAD 4
#define NEG 0.2f

typedef __bf16 bf16x8 __attribute__((ext_vector_type(8)));
typedef __bf16 bf16x4 __attribute__((ext_vector_type(4)));
typedef float f32x4 __attribute__((ext_vector_type(4)));

__device__ __forceinline__ float blo(unsigned u) { return __uint_as_float(u << 16); }
__device__ __forceinline__ float bhi(unsigned u) { return __uint_as_float(u & 0xffff0000u); }

// ---------------- CSR build ----------------

__global__ __launch_bounds__(256) void hist_k(const int* __restrict__ dst,
                                              int* __restrict__ deg, int E) {
    int e = blockIdx.x * 256 + threadIdx.x;
    if (e < E) atomicAdd(&deg[dst[e]], 1);
}

// Phase A: per-block (2048 elems) totals
__global__ __launch_bounds__(256) void partial_k(const int* __restrict__ deg,
                                                 int* __restrict__ bsum, int n) {
    int t = threadIdx.x;
    int base = blockIdx.x * 2048 + t * 8;
    int s = 0;
#pragma unroll
    for (int i = 0; i < 8; ++i) {
        int idx = base + i;
        if (idx < n) s += deg[idx];
    }
#pragma unroll
    for (int off = 32; off; off >>= 1) s += __shfl_down(s, off, 64);
    __shared__ int ws[4];
    if ((t & 63) == 0) ws[t >> 6] = s;
    __syncthreads();
    if (t == 0) bsum[blockIdx.x] = ws[0] + ws[1] + ws[2] + ws[3];
}

// Phase B: exclusive scan of block sums (nb <= 256), one block
__global__ __launch_bounds__(256) void bscan_k(const int* __restrict__ bsum,
                                               int* __restrict__ boff, int nb) {
    __shared__ int sh[256];
    int t = threadIdx.x;
    int v = (t < nb) ? bsum[t] : 0;
    sh[t] = v;
    __syncthreads();
    for (int off = 1; off < 256; off <<= 1) {
        int u = (t >= off) ? sh[t - off] : 0;
        __syncthreads();
        sh[t] += u;
        __syncthreads();
    }
    if (t < nb) boff[t] = sh[t] - v;  // exclusive
}

// Phase C: block-local rescan + offset, write rowptr & fill
__global__ __launch_bounds__(256) void rescan_k(const int* __restrict__ deg,
                                                const int* __restrict__ boff,
                                                int* __restrict__ rowptr,
                                                int* __restrict__ fill,
                                                int n, int total) {
    __shared__ int ts[256];
    int t = threadIdx.x;
    int base = blockIdx.x * 2048 + t * 8;
    int v[8];
    int s = 0;
#pragma unroll
    for (int i = 0; i < 8; ++i) {
        int idx = base + i;
        v[i] = (idx < n) ? deg[idx] : 0;
        s += v[i];
    }
    ts[t] = s;
    __syncthreads();
    for (int off = 1; off < 256; off <<= 1) {
        int u = (t >= off) ? ts[t - off] : 0;
        __syncthreads();
        ts[t] += u;
        __syncthreads();
    }
    int run = boff[blockIdx.x] + ts[t] - s;  // exclusive prefix for this thread
#pragma unroll
    for (int i = 0; i < 8; ++i) {
        int idx = base + i;
        if (idx < n) {
            rowptr[idx] = run;
            fill[idx] = run;
            run += v[i];
        }
    }
    if (blockIdx.x == 0 && t == 0) rowptr[n] = total;
}

__global__ __launch_bounds__(256) void scatter_k(const int* __restrict__ src,
                                                 const int* __restrict__ dst,
                                                 const float* __restrict__ ew,
                                                 int* __restrict__ fill,
                                                 int* __restrict__ srcs,
                                                 float* __restrict__ wsrt, int E) {
    int e = blockIdx.x * 256 + threadIdx.x;
    if (e < E) {
        int d = dst[e];
        int p = atomicAdd(&fill[d], 1);
        srcs[p] = src[e];
        wsrt[p] = ew[e];
    }
}

// ---------------- W pack: [K][M] f32 -> [n][k] bf16 ----------------

__global__ __launch_bounds__(256) void wpack_k(const float* __restrict__ W,
                                               __hip_bfloat16* __restrict__ Wp,
                                               int K, int M) {
    int tid = blockIdx.x * 256 + threadIdx.x;
    if (tid >= K * M) return;
    int k = tid / M, n = tid - k * M;
    ((__bf16*)Wp)[(size_t)n * K + k] = (__bf16)W[tid];
}

// ---------------- MFMA GEMM: h_bf16t[N][d*4+head] = X[N,K] @ W[K,4D] + b ----------------
// One wave per 16-row strip. Head-interleaved n-tiles: chunk c covers output
// cols d in [c*16, c*16+16) x 4 heads -> contiguous 64 bf16 in h layout.
// Split-A (hi+lo bf16) for near-f32 precision on the X side.

template <int K, int D>
__global__ __launch_bounds__(256) void gemm_mfma_k(const float* __restrict__ X,
                                                   const __hip_bfloat16* __restrict__ Wp,
                                                   const float* __restrict__ bias,
                                                   __hip_bfloat16* __restrict__ out,
                                                   int nrows) {
    constexpr int M = 4 * D;
    constexpr int KS = K / 32;
    constexpr int NC = D / 16;
    int wid = threadIdx.x >> 6, lane = threadIdx.x & 63;
    int strip = blockIdx.x * 4 + wid;
    int r0 = strip * 16;
    if (r0 >= nrows) return;
    int lrow = lane & 15;
    int lk = (lane >> 4) * 8;

    // A fragments, split hi/lo
    bf16x8 ah[KS], al[KS];
    const float* xp = X + (size_t)(r0 + lrow) * K + lk;
#pragma unroll
    for (int ks = 0; ks < KS; ++ks) {
        f32x4 f0 = *(const f32x4*)(xp + ks * 32);
        f32x4 f1 = *(const f32x4*)(xp + ks * 32 + 4);
#pragma unroll
        for (int j = 0; j < 4; ++j) {
            __bf16 h0 = (__bf16)f0[j];
            __bf16 h1 = (__bf16)f1[j];
            ah[ks][j] = h0;
            ah[ks][4 + j] = h1;
            al[ks][j] = (__bf16)(f0[j] - (float)h0);
            al[ks][4 + j] = (__bf16)(f1[j] - (float)h1);
        }
    }

    const __bf16* wp = (const __bf16*)Wp;
    __bf16* op = (__bf16*)out;

#pragma unroll
    for (int c = 0; c < NC; ++c) {
        f32x4 acc[4];
#pragma unroll
        for (int t = 0; t < 4; ++t)
#pragma unroll
            for (int r = 0; r < 4; ++r) acc[t][r] = 0.f;

#pragma unroll
        for (int ks = 0; ks < KS; ++ks) {
#pragma unroll
            for (int t = 0; t < 4; ++t) {
                int n = t * D + c * 16 + lrow;
                bf16x8 bfr = *(const bf16x8*)(wp + (size_t)n * K + ks * 32 + lk);
                acc[t] = __builtin_amdgcn_mfma_f32_16x16x32_bf16(ah[ks], bfr, acc[t], 0, 0, 0);
                acc[t] = __builtin_amdgcn_mfma_f32_16x16x32_bf16(al[ks], bfr, acc[t], 0, 0, 0);
            }
        }

        float bv[4];
#pragma unroll
        for (int t = 0; t < 4; ++t) bv[t] = bias[t * D + c * 16 + lrow];

#pragma unroll
        for (int r = 0; r < 4; ++r) {
            bf16x4 o;
#pragma unroll
            for (int t = 0; t < 4; ++t) o[t] = (__bf16)(acc[t][r] + bv[t]);
            int row = r0 + (lane >> 4) * 4 + r;
            *(bf16x4*)(op + (size_t)row * M + (size_t)(c * 16 + lrow) * 4) = o;
        }
    }
}

// ---------------- per-node scores from transposed bf16 h ----------------

template <int D>
__global__ __launch_bounds__(256) void score_t_k(const __hip_bfloat16* __restrict__ h,
                                                 const float* __restrict__ att,
                                                 float* __restrict__ s, int n) {
    int gt = blockIdx.x * 256 + threadIdx.x;
    int node = gt >> 6, lane = gt & 63;
    if (node >= n) return;
    const uint2* hp = (const uint2*)(h + (size_t)node * (4 * D));
    float p0 = 0.f, p1 = 0.f, p2 = 0.f, p3 = 0.f;
#pragma unroll
    for (int dd = 0; dd < D / 64; ++dd) {
        int d = dd * 64 + lane;
        uint2 u = hp[d];
        p0 += blo(u.x) * att[0 * D + d];
        p1 += bhi(u.x) * att[1 * D + d];
        p2 += blo(u.y) * att[2 * D + d];
        p3 += bhi(u.y) * att[3 * D + d];
    }
#pragma unroll
    for (int off = 32; off; off >>= 1) {
        p0 += __shfl_xor(p0, off, 64);
        p1 += __shfl_xor(p1, off, 64);
        p2 += __shfl_xor(p2, off, 64);
        p3 += __shfl_xor(p3, off, 64);
    }
    if (lane == 0) {
        *(float4*)&s[(size_t)node * NHEAD] = make_float4(p0, p1, p2, p3);
    }
}

// ---------------- per-edge alpha: leaky, *w, softmax over heads, /H ----------------

__global__ __launch_bounds__(256) void alpha_k(const int* __restrict__ srcs,
                                               const float* __restrict__ wsrt,
                                               const float* __restrict__ s,
                                               float* __restrict__ alpha, int E) {
    int e = blockIdx.x * 256 + threadIdx.x;
    if (e >= E) return;
    int sn = srcs[e];
    float w = wsrt[e];
    float4 sv = *(const float4*)&s[(size_t)sn * NHEAD];
    float a0 = (sv.x > 0.f ? sv.x : NEG * sv.x) * w;
    float a1 = (sv.y > 0.f ? sv.y : NEG * sv.y) * w;
    float a2 = (sv.z > 0.f ? sv.z : NEG * sv.z) * w;
    float a3 = (sv.w > 0.f ? sv.w : NEG * sv.w) * w;
    float m = fmaxf(fmaxf(a0, a1), fmaxf(a2, a3));
    float e0 = __expf(a0 - m), e1 = __expf(a1 - m);
    float e2 = __expf(a2 - m), e3 = __expf(a3 - m);
    float inv = 0.25f / (e0 + e1 + e2 + e3);  // fold mean-over-heads
    *(float4*)&alpha[(size_t)e * 4] = make_float4(e0 * inv, e1 * inv, e2 * inv, e3 * inv);
}

// ---------------- per-node aggregation (wave per node, lane = dim) ----------------

template <int D, bool RELU>
__global__ __launch_bounds__(256) void aggr_t_k(const int* __restrict__ rowptr,
                                                const int* __restrict__ srcs,
                                                const float* __restrict__ alpha,
                                                const __hip_bfloat16* __restrict__ h,
                                                float* __restrict__ out, int n) {
    int gt = blockIdx.x * 256 + threadIdx.x;
    int node = gt >> 6, lane = gt & 63;
    if (node >= n) return;
    int beg = rowptr[node], end = rowptr[node + 1];

    if (D == 64) {
        const uint2* hp = (const uint2*)h;  // node stride = D uint2
        float acc = 0.f, accB = 0.f;
        int e = beg;
        for (; e + 1 < end; e += 2) {
            int snA = srcs[e], snB = srcs[e + 1];
            float4 alA = *(const float4*)&alpha[(size_t)e * 4];
            float4 alB = *(const float4*)&alpha[(size_t)(e + 1) * 4];
            uint2 uA = hp[(size_t)snA * 64 + lane];
            uint2 uB = hp[(size_t)snB * 64 + lane];
            acc  += alA.x * blo(uA.x) + alA.y * bhi(uA.x) + alA.z * blo(uA.y) + alA.w * bhi(uA.y);
            accB += alB.x * blo(uB.x) + alB.y * bhi(uB.x) + alB.z * blo(uB.y) + alB.w * bhi(uB.y);
        }
        if (e < end) {
            int sn = srcs[e];
            float4 al = *(const float4*)&alpha[(size_t)e * 4];
            uint2 u = hp[(size_t)sn * 64 + lane];
            acc += al.x * blo(u.x) + al.y * bhi(u.x) + al.z * blo(u.y) + al.w * bhi(u.y);
        }
        float v = acc + accB;
        if (RELU) v = fmaxf(v, 0.f);
        out[(size_t)node * 64 + lane] = v;
    } else {
        // D == 128: lane owns dims 2*lane, 2*lane+1; 16B load covers both (4 heads each)
        const uint4* hp = (const uint4*)h;  // node stride = 64 uint4
        float acc0 = 0.f, acc1 = 0.f;
        for (int e = beg; e < end; ++e) {
            int sn = srcs[e];
            float4 al = *(const float4*)&alpha[(size_t)e * 4];
            uint4 u = hp[(size_t)sn * 64 + lane];
            acc0 += al.x * blo(u.x) + al.y * bhi(u.x) + al.z * blo(u.y) + al.w * bhi(u.y);
            acc1 += al.x * blo(u.z) + al.y * bhi(u.z) + al.z * blo(u.w) + al.w * bhi(u.w);
        }
        float2 v = make_float2(acc0, acc1);
        if (RELU) { v.x = fmaxf(v.x, 0.f); v.y = fmaxf(v.y, 0.f); }
        *(float2*)&out[(size_t)node * 128 + lane * 2] = v;
    }
}

// ---------------- launch ----------------

extern "C" void kernel_launch(void* const* d_in, const int* in_sizes, int n_in,
                              void* d_out, int out_size, void* d_ws, size_t ws_size,
                              hipStream_t stream) {
    const float* x    = (const float*)d_in[0];
    const int*   ei   = (const int*)d_in[1];
    const float* ew   = (const float*)d_in[2];
    const float* W1   = (const float*)d_in[3];
    const float* b1   = (const float*)d_in[4];
    const float* att1 = (const float*)d_in[5];
    const float* W2   = (const float*)d_in[6];
    const float* b2   = (const float*)d_in[7];
    const float* att2 = (const float*)d_in[8];
    const float* W3   = (const float*)d_in[9];
    const float* b3   = (const float*)d_in[10];
    const float* att3 = (const float*)d_in[11];

    const int N = in_sizes[0] / 128;
    const int E = in_sizes[2];
    const int* src = ei;
    const int* dst = ei + E;

    char* wp = (char*)d_ws;
    auto alloc = [&](size_t bytes) -> void* {
        void* p = (void*)wp;
        wp += (bytes + 511) & ~(size_t)511;
        return p;
    };
    int*   deg    = (int*)alloc((size_t)N * 4);
    int*   rowptr = (int*)alloc((size_t)(N + 1) * 4);
    int*   fill   = (int*)alloc((size_t)N * 4);
    int*   bsum   = (int*)alloc(256 * 4);
    int*   boff   = (int*)alloc(256 * 4);
    int*   srcs   = (int*)alloc((size_t)E * 4);
    float* wsrt   = (float*)alloc((size_t)E * 4);
    __hip_bfloat16* h = (__hip_bfloat16*)alloc((size_t)N * 512 * 2);  // max H*OUT bf16
    float* s      = (float*)alloc((size_t)N * NHEAD * 4);
    float* alpha  = (float*)alloc((size_t)E * 4 * 4);
    float* a1     = (float*)alloc((size_t)N * 64 * 4);
    float* a2     = (float*)alloc((size_t)N * 64 * 4);
    __hip_bfloat16* Wp1 = (__hip_bfloat16*)alloc(128 * 256 * 2);
    __hip_bfloat16* Wp2 = (__hip_bfloat16*)alloc(64 * 256 * 2);
    __hip_bfloat16* Wp3 = (__hip_bfloat16*)alloc(64 * 512 * 2);

    // --- W packs (independent of CSR) ---
    wpack_k<<<(128 * 256 + 255) / 256, 256, 0, stream>>>(W1, Wp1, 128, 256);
    wpack_k<<<(64 * 256 + 255) / 256, 256, 0, stream>>>(W2, Wp2, 64, 256);
    wpack_k<<<(64 * 512 + 255) / 256, 256, 0, stream>>>(W3, Wp3, 64, 512);

    // --- CSR build (shared by all 3 layers) ---
    hipMemsetAsync(deg, 0, (size_t)N * 4, stream);
    int ge = (E + 255) / 256;
    int nb = (N + 2047) / 2048;  // scan blocks (<=256 supported)
    hist_k<<<ge, 256, 0, stream>>>(dst, deg, E);
    partial_k<<<nb, 256, 0, stream>>>(deg, bsum, N);
    bscan_k<<<1, 256, 0, stream>>>(bsum, boff, nb);
    rescan_k<<<nb, 256, 0, stream>>>(deg, boff, rowptr, fill, N, E);
    scatter_k<<<ge, 256, 0, stream>>>(src, dst, ew, fill, srcs, wsrt, E);

    int gm = ((N + 15) / 16 + 3) / 4;   // MFMA GEMM: 16-row strip per wave, 4 waves/block
    int ga = (N * 64 + 255) / 256;

    // --- layer 1: IN=128 -> H*64 ---
    gemm_mfma_k<128, 64><<<gm, 256, 0, stream>>>(x, Wp1, b1, h, N);
    score_t_k<64><<<ga, 256, 0, stream>>>(h, att1, s, N);
    alpha_k<<<ge, 256, 0, stream>>>(srcs, wsrt, s, alpha, E);
    aggr_t_k<64, true><<<ga, 256, 0, stream>>>(rowptr, srcs, alpha, h, a1, N);

    // --- layer 2: 64 -> H*64 ---
    gemm_mfma_k<64, 64><<<gm, 256, 0, stream>>>(a1, Wp2, b2, h, N);
    score_t_k<64><<<ga, 256, 0, stream>>>(h, att2, s, N);
    alpha_k<<<ge, 256, 0, stream>>>(srcs, wsrt, s, alpha, E);
    aggr_t_k<64, true><<<ga, 256, 0, stream>>>(rowptr, srcs, alpha, h, a2, N);

    // --- layer 3: 64 -> H*128 ---
    gemm_mfma_k<64, 128><<<gm, 256, 0, stream>>>(a2, Wp3, b3, h, N);
    score_t_k<128><<<ga, 256, 0, stream>>>(h, att3, s, N);
    alpha_k<<<ge, 256, 0, stream>>>(srcs, wsrt, s, alpha, E);
    aggr_t_k<128, false><<<ga, 256, 0, stream>>>(rowptr, srcs, alpha, h, (float*)d_out, N);
}

// Round 5
// 347.374 us; speedup vs baseline: 2.1878x; 1.1462x over previous
//
#include <hip/hip_runtime.h>
#include <hip/hip_bf16.h>

#define NHEAD 4
#define NEG 0.2f

typedef __bf16 bf16x8 __attribute__((ext_vector_type(8)));
typedef __bf16 bf16x4 __attribute__((ext_vector_type(4)));
typedef float f32x4 __attribute__((ext_vector_type(4)));

__device__ __forceinline__ float blo(unsigned u) { return __uint_as_float(u << 16); }
__device__ __forceinline__ float bhi(unsigned u) { return __uint_as_float(u & 0xffff0000u); }

// ---------------- CSR build ----------------

__global__ __launch_bounds__(256) void hist_k(const int* __restrict__ dst,
                                              int* __restrict__ deg, int E) {
    int e = blockIdx.x * 256 + threadIdx.x;
    if (e < E) atomicAdd(&deg[dst[e]], 1);
}

__global__ __launch_bounds__(256) void partial_k(const int* __restrict__ deg,
                                                 int* __restrict__ bsum, int n) {
    int t = threadIdx.x;
    int base = blockIdx.x * 2048 + t * 8;
    int s = 0;
#pragma unroll
    for (int i = 0; i < 8; ++i) {
        int idx = base + i;
        if (idx < n) s += deg[idx];
    }
#pragma unroll
    for (int off = 32; off; off >>= 1) s += __shfl_down(s, off, 64);
    __shared__ int ws[4];
    if ((t & 63) == 0) ws[t >> 6] = s;
    __syncthreads();
    if (t == 0) bsum[blockIdx.x] = ws[0] + ws[1] + ws[2] + ws[3];
}

__global__ __launch_bounds__(256) void bscan_k(const int* __restrict__ bsum,
                                               int* __restrict__ boff, int nb) {
    __shared__ int sh[256];
    int t = threadIdx.x;
    int v = (t < nb) ? bsum[t] : 0;
    sh[t] = v;
    __syncthreads();
    for (int off = 1; off < 256; off <<= 1) {
        int u = (t >= off) ? sh[t - off] : 0;
        __syncthreads();
        sh[t] += u;
        __syncthreads();
    }
    if (t < nb) boff[t] = sh[t] - v;  // exclusive
}

__global__ __launch_bounds__(256) void rescan_k(const int* __restrict__ deg,
                                                const int* __restrict__ boff,
                                                int* __restrict__ rowptr,
                                                int* __restrict__ fill,
                                                int n, int total) {
    __shared__ int ts[256];
    int t = threadIdx.x;
    int base = blockIdx.x * 2048 + t * 8;
    int v[8];
    int s = 0;
#pragma unroll
    for (int i = 0; i < 8; ++i) {
        int idx = base + i;
        v[i] = (idx < n) ? deg[idx] : 0;
        s += v[i];
    }
    ts[t] = s;
    __syncthreads();
    for (int off = 1; off < 256; off <<= 1) {
        int u = (t >= off) ? ts[t - off] : 0;
        __syncthreads();
        ts[t] += u;
        __syncthreads();
    }
    int run = boff[blockIdx.x] + ts[t] - s;
#pragma unroll
    for (int i = 0; i < 8; ++i) {
        int idx = base + i;
        if (idx < n) {
            rowptr[idx] = run;
            fill[idx] = run;
            run += v[i];
        }
    }
    if (blockIdx.x == 0 && t == 0) rowptr[n] = total;
}

__global__ __launch_bounds__(256) void scatter_k(const int* __restrict__ src,
                                                 const int* __restrict__ dst,
                                                 const float* __restrict__ ew,
                                                 int* __restrict__ fill,
                                                 int* __restrict__ srcs,
                                                 float* __restrict__ wsrt, int E) {
    int e = blockIdx.x * 256 + threadIdx.x;
    if (e < E) {
        int d = dst[e];
        int p = atomicAdd(&fill[d], 1);
        srcs[p] = src[e];
        wsrt[p] = ew[e];
    }
}

// ---------------- fused W pack: [K][M] f32 -> [n][k] bf16, all 3 layers ----------------

__device__ __forceinline__ void wpack1(const float* W, __bf16* Wp, int K, int M, int tid) {
    int k = tid / M, n = tid - k * M;
    Wp[(size_t)n * K + k] = (__bf16)W[tid];
}

__global__ __launch_bounds__(256) void wpack3_k(const float* __restrict__ W1,
                                                const float* __restrict__ W2,
                                                const float* __restrict__ W3,
                                                __hip_bfloat16* __restrict__ Wp1,
                                                __hip_bfloat16* __restrict__ Wp2,
                                                __hip_bfloat16* __restrict__ Wp3) {
    int tid = blockIdx.x * 256 + threadIdx.x;
    if (tid < 32768) wpack1(W1, (__bf16*)Wp1, 128, 256, tid);
    else if (tid < 49152) wpack1(W2, (__bf16*)Wp2, 64, 256, tid - 32768);
    else if (tid < 81920) wpack1(W3, (__bf16*)Wp3, 64, 512, tid - 49152);
}

// ---------------- MFMA GEMM + fused score ----------------
// h_bf16t[N][d*4+head] = X[N,K] @ W[K,4D] + b ; s[N][4] = per-head dot(h, att).
// One wave per 16-row strip; head-interleaved n-tiles; split-A hi/lo for precision.

template <int K, int D>
__global__ __launch_bounds__(256) void gemm_mfma_k(const float* __restrict__ X,
                                                   const __hip_bfloat16* __restrict__ Wp,
                                                   const float* __restrict__ bias,
                                                   const float* __restrict__ att,
                                                   __hip_bfloat16* __restrict__ out,
                                                   float* __restrict__ s,
                                                   int nrows) {
    constexpr int M = 4 * D;
    constexpr int KS = K / 32;
    constexpr int NC = D / 16;
    int wid = threadIdx.x >> 6, lane = threadIdx.x & 63;
    int strip = blockIdx.x * 4 + wid;
    int r0 = strip * 16;
    if (r0 >= nrows) return;
    int lrow = lane & 15;
    int lk = (lane >> 4) * 8;

    // A fragments, split hi/lo
    bf16x8 ah[KS], al[KS];
    const float* xp = X + (size_t)(r0 + lrow) * K + lk;
#pragma unroll
    for (int ks = 0; ks < KS; ++ks) {
        f32x4 f0 = *(const f32x4*)(xp + ks * 32);
        f32x4 f1 = *(const f32x4*)(xp + ks * 32 + 4);
#pragma unroll
        for (int j = 0; j < 4; ++j) {
            __bf16 h0 = (__bf16)f0[j];
            __bf16 h1 = (__bf16)f1[j];
            ah[ks][j] = h0;
            ah[ks][4 + j] = h1;
            al[ks][j] = (__bf16)(f0[j] - (float)h0);
            al[ks][4 + j] = (__bf16)(f1[j] - (float)h1);
        }
    }

    const __bf16* wp = (const __bf16*)Wp;
    __bf16* op = (__bf16*)out;

    float sc[4][4];  // [head][r] score partials
#pragma unroll
    for (int t = 0; t < 4; ++t)
#pragma unroll
        for (int r = 0; r < 4; ++r) sc[t][r] = 0.f;

#pragma unroll
    for (int c = 0; c < NC; ++c) {
        f32x4 acc[4];
#pragma unroll
        for (int t = 0; t < 4; ++t)
#pragma unroll
            for (int r = 0; r < 4; ++r) acc[t][r] = 0.f;

#pragma unroll
        for (int ks = 0; ks < KS; ++ks) {
#pragma unroll
            for (int t = 0; t < 4; ++t) {
                int n = t * D + c * 16 + lrow;
                bf16x8 bfr = *(const bf16x8*)(wp + (size_t)n * K + ks * 32 + lk);
                acc[t] = __builtin_amdgcn_mfma_f32_16x16x32_bf16(ah[ks], bfr, acc[t], 0, 0, 0);
                acc[t] = __builtin_amdgcn_mfma_f32_16x16x32_bf16(al[ks], bfr, acc[t], 0, 0, 0);
            }
        }

        float bv[4], attv[4];
#pragma unroll
        for (int t = 0; t < 4; ++t) {
            bv[t] = bias[t * D + c * 16 + lrow];
            attv[t] = att[t * D + c * 16 + lrow];
        }

#pragma unroll
        for (int r = 0; r < 4; ++r) {
            bf16x4 o;
#pragma unroll
            for (int t = 0; t < 4; ++t) {
                float hv = acc[t][r] + bv[t];
                o[t] = (__bf16)hv;
                sc[t][r] += hv * attv[t];
            }
            int row = r0 + (lane >> 4) * 4 + r;
            if (row < nrows)
                *(bf16x4*)(op + (size_t)row * M + (size_t)(c * 16 + lrow) * 4) = o;
        }
    }

    // reduce score partials over the 16-lane column group
#pragma unroll
    for (int m = 1; m < 16; m <<= 1) {
#pragma unroll
        for (int t = 0; t < 4; ++t)
#pragma unroll
            for (int r = 0; r < 4; ++r) sc[t][r] += __shfl_xor(sc[t][r], m, 64);
    }
    int g = lane >> 4;
#pragma unroll
    for (int r = 0; r < 4; ++r) {
        if (lrow == r) {
            int row = r0 + g * 4 + r;
            if (row < nrows)
                *(float4*)&s[(size_t)row * 4] = make_float4(sc[0][r], sc[1][r], sc[2][r], sc[3][r]);
        }
    }
}

// ---------------- per-edge alpha: leaky, *w, softmax over heads, /H ----------------

__global__ __launch_bounds__(256) void alpha_k(const int* __restrict__ srcs,
                                               const float* __restrict__ wsrt,
                                               const float* __restrict__ s,
                                               float* __restrict__ alpha, int E) {
    int e = blockIdx.x * 256 + threadIdx.x;
    if (e >= E) return;
    int sn = srcs[e];
    float w = wsrt[e];
    float4 sv = *(const float4*)&s[(size_t)sn * NHEAD];
    float a0 = (sv.x > 0.f ? sv.x : NEG * sv.x) * w;
    float a1 = (sv.y > 0.f ? sv.y : NEG * sv.y) * w;
    float a2 = (sv.z > 0.f ? sv.z : NEG * sv.z) * w;
    float a3 = (sv.w > 0.f ? sv.w : NEG * sv.w) * w;
    float m = fmaxf(fmaxf(a0, a1), fmaxf(a2, a3));
    float e0 = __expf(a0 - m), e1 = __expf(a1 - m);
    float e2 = __expf(a2 - m), e3 = __expf(a3 - m);
    float inv = 0.25f / (e0 + e1 + e2 + e3);  // fold mean-over-heads
    *(float4*)&alpha[(size_t)e * 4] = make_float4(e0 * inv, e1 * inv, e2 * inv, e3 * inv);
}

// ---------------- aggregation: half-wave (32 lanes) per node ----------------
// lane owns dims {2*lid, 2*lid+1} (+ {64+2*lid, 65+2*lid} for D=128); one
// uint4 (16B) per row-chunk per edge -> 2 nodes x 2-edge unroll = 4 gather
// streams in flight per wave.

template <int D, bool RELU>
__global__ __launch_bounds__(256) void aggr_hw_k(const int* __restrict__ rowptr,
                                                 const int* __restrict__ srcs,
                                                 const float* __restrict__ alpha,
                                                 const __hip_bfloat16* __restrict__ h,
                                                 float* __restrict__ out, int n) {
    int gt = blockIdx.x * 256 + threadIdx.x;
    int node = gt >> 5;
    int lid = gt & 31;
    if (node >= n) return;
    int beg = rowptr[node], end = rowptr[node + 1];
    constexpr int STR = D / 2;  // uint4 per node row
    const uint4* hp = (const uint4*)h;

    float a00 = 0.f, a01 = 0.f, a10 = 0.f, a11 = 0.f;
    int e = beg;
    for (; e + 1 < end; e += 2) {
        int snA = srcs[e], snB = srcs[e + 1];
        float4 alA = *(const float4*)&alpha[(size_t)e * 4];
        float4 alB = *(const float4*)&alpha[(size_t)(e + 1) * 4];
        uint4 uA0 = hp[(size_t)snA * STR + lid];
        uint4 uB0 = hp[(size_t)snB * STR + lid];
        if (D == 128) {
            uint4 uA1 = hp[(size_t)snA * STR + 32 + lid];
            uint4 uB1 = hp[(size_t)snB * STR + 32 + lid];
            a10 += alA.x * blo(uA1.x) + alA.y * bhi(uA1.x) + alA.z * blo(uA1.y) + alA.w * bhi(uA1.y);
            a11 += alA.x * blo(uA1.z) + alA.y * bhi(uA1.z) + alA.z * blo(uA1.w) + alA.w * bhi(uA1.w);
            a10 += alB.x * blo(uB1.x) + alB.y * bhi(uB1.x) + alB.z * blo(uB1.y) + alB.w * bhi(uB1.y);
            a11 += alB.x * blo(uB1.z) + alB.y * bhi(uB1.z) + alB.z * blo(uB1.w) + alB.w * bhi(uB1.w);
        }
        a00 += alA.x * blo(uA0.x) + alA.y * bhi(uA0.x) + alA.z * blo(uA0.y) + alA.w * bhi(uA0.y);
        a01 += alA.x * blo(uA0.z) + alA.y * bhi(uA0.z) + alA.z * blo(uA0.w) + alA.w * bhi(uA0.w);
        a00 += alB.x * blo(uB0.x) + alB.y * bhi(uB0.x) + alB.z * blo(uB0.y) + alB.w * bhi(uB0.y);
        a01 += alB.x * blo(uB0.z) + alB.y * bhi(uB0.z) + alB.z * blo(uB0.w) + alB.w * bhi(uB0.w);
    }
    if (e < end) {
        int sn = srcs[e];
        float4 al = *(const float4*)&alpha[(size_t)e * 4];
        uint4 u0 = hp[(size_t)sn * STR + lid];
        if (D == 128) {
            uint4 u1 = hp[(size_t)sn * STR + 32 + lid];
            a10 += al.x * blo(u1.x) + al.y * bhi(u1.x) + al.z * blo(u1.y) + al.w * bhi(u1.y);
            a11 += al.x * blo(u1.z) + al.y * bhi(u1.z) + al.z * blo(u1.w) + al.w * bhi(u1.w);
        }
        a00 += al.x * blo(u0.x) + al.y * bhi(u0.x) + al.z * blo(u0.y) + al.w * bhi(u0.y);
        a01 += al.x * blo(u0.z) + al.y * bhi(u0.z) + al.z * blo(u0.w) + al.w * bhi(u0.w);
    }

    if (RELU) {
        a00 = fmaxf(a00, 0.f); a01 = fmaxf(a01, 0.f);
        a10 = fmaxf(a10, 0.f); a11 = fmaxf(a11, 0.f);
    }
    *(float2*)&out[(size_t)node * D + 2 * lid] = make_float2(a00, a01);
    if (D == 128)
        *(float2*)&out[(size_t)node * D + 64 + 2 * lid] = make_float2(a10, a11);
}

// ---------------- launch ----------------

extern "C" void kernel_launch(void* const* d_in, const int* in_sizes, int n_in,
                              void* d_out, int out_size, void* d_ws, size_t ws_size,
                              hipStream_t stream) {
    const float* x    = (const float*)d_in[0];
    const int*   ei   = (const int*)d_in[1];
    const float* ew   = (const float*)d_in[2];
    const float* W1   = (const float*)d_in[3];
    const float* b1   = (const float*)d_in[4];
    const float* att1 = (const float*)d_in[5];
    const float* W2   = (const float*)d_in[6];
    const float* b2   = (const float*)d_in[7];
    const float* att2 = (const float*)d_in[8];
    const float* W3   = (const float*)d_in[9];
    const float* b3   = (const float*)d_in[10];
    const float* att3 = (const float*)d_in[11];

    const int N = in_sizes[0] / 128;
    const int E = in_sizes[2];
    const int* src = ei;
    const int* dst = ei + E;

    char* wp = (char*)d_ws;
    auto alloc = [&](size_t bytes) -> void* {
        void* p = (void*)wp;
        wp += (bytes + 511) & ~(size_t)511;
        return p;
    };
    int*   deg    = (int*)alloc((size_t)N * 4);
    int*   rowptr = (int*)alloc((size_t)(N + 1) * 4);
    int*   fill   = (int*)alloc((size_t)N * 4);
    int*   bsum   = (int*)alloc(256 * 4);
    int*   boff   = (int*)alloc(256 * 4);
    int*   srcs   = (int*)alloc((size_t)E * 4);
    float* wsrt   = (float*)alloc((size_t)E * 4);
    __hip_bfloat16* h = (__hip_bfloat16*)alloc((size_t)N * 512 * 2);
    float* s      = (float*)alloc((size_t)N * NHEAD * 4);
    float* alpha  = (float*)alloc((size_t)E * 4 * 4);
    float* a1     = (float*)alloc((size_t)N * 64 * 4);
    float* a2     = (float*)alloc((size_t)N * 64 * 4);
    __hip_bfloat16* Wp1 = (__hip_bfloat16*)alloc(128 * 256 * 2);
    __hip_bfloat16* Wp2 = (__hip_bfloat16*)alloc(64 * 256 * 2);
    __hip_bfloat16* Wp3 = (__hip_bfloat16*)alloc(64 * 512 * 2);

    // --- W packs (one kernel) ---
    wpack3_k<<<320, 256, 0, stream>>>(W1, W2, W3, Wp1, Wp2, Wp3);

    // --- CSR build (shared by all 3 layers) ---
    hipMemsetAsync(deg, 0, (size_t)N * 4, stream);
    int ge = (E + 255) / 256;
    int nb = (N + 2047) / 2048;
    hist_k<<<ge, 256, 0, stream>>>(dst, deg, E);
    partial_k<<<nb, 256, 0, stream>>>(deg, bsum, N);
    bscan_k<<<1, 256, 0, stream>>>(bsum, boff, nb);
    rescan_k<<<nb, 256, 0, stream>>>(deg, boff, rowptr, fill, N, E);
    scatter_k<<<ge, 256, 0, stream>>>(src, dst, ew, fill, srcs, wsrt, E);

    int gm = ((N + 15) / 16 + 3) / 4;
    int ga = (N * 32 + 255) / 256;   // half-wave per node

    // --- layer 1: IN=128 -> H*64 ---
    gemm_mfma_k<128, 64><<<gm, 256, 0, stream>>>(x, Wp1, b1, att1, h, s, N);
    alpha_k<<<ge, 256, 0, stream>>>(srcs, wsrt, s, alpha, E);
    aggr_hw_k<64, true><<<ga, 256, 0, stream>>>(rowptr, srcs, alpha, h, a1, N);

    // --- layer 2: 64 -> H*64 ---
    gemm_mfma_k<64, 64><<<gm, 256, 0, stream>>>(a1, Wp2, b2, att2, h, s, N);
    alpha_k<<<ge, 256, 0, stream>>>(srcs, wsrt, s, alpha, E);
    aggr_hw_k<64, true><<<ga, 256, 0, stream>>>(rowptr, srcs, alpha, h, a2, N);

    // --- layer 3: 64 -> H*128 ---
    gemm_mfma_k<64, 128><<<gm, 256, 0, stream>>>(a2, Wp3, b3, att3, h, s, N);
    alpha_k<<<ge, 256, 0, stream>>>(srcs, wsrt, s, alpha, E);
    aggr_hw_k<128, false><<<ga, 256, 0, stream>>>(rowptr, srcs, alpha, h, (float*)d_out, N);
}

// Round 6
// 315.302 us; speedup vs baseline: 2.4104x; 1.1017x over previous
//
#include <hip/hip_runtime.h>
#include <hip/hip_bf16.h>

#define NHEAD 4
#define NEG 0.2f

typedef __bf16 bf16x8 __attribute__((ext_vector_type(8)));
typedef float f32x4 __attribute__((ext_vector_type(4)));

__device__ __forceinline__ float blo(unsigned u) { return __uint_as_float(u << 16); }
__device__ __forceinline__ float bhi(unsigned u) { return __uint_as_float(u & 0xffff0000u); }
__device__ __forceinline__ unsigned short fbits(float f) {
    __bf16 h = (__bf16)f;
    return *(unsigned short*)&h;
}

// ---------------- CSR build ----------------

__global__ __launch_bounds__(256) void hist_k(const int* __restrict__ dst,
                                              int* __restrict__ deg, int E) {
    int e = blockIdx.x * 256 + threadIdx.x;
    if (e < E) atomicAdd(&deg[dst[e]], 1);
}

__global__ __launch_bounds__(256) void partial_k(const int* __restrict__ deg,
                                                 int* __restrict__ bsum, int n) {
    int t = threadIdx.x;
    int base = blockIdx.x * 2048 + t * 8;
    int s = 0;
#pragma unroll
    for (int i = 0; i < 8; ++i) {
        int idx = base + i;
        if (idx < n) s += deg[idx];
    }
#pragma unroll
    for (int off = 32; off; off >>= 1) s += __shfl_down(s, off, 64);
    __shared__ int ws[4];
    if ((t & 63) == 0) ws[t >> 6] = s;
    __syncthreads();
    if (t == 0) bsum[blockIdx.x] = ws[0] + ws[1] + ws[2] + ws[3];
}

__global__ __launch_bounds__(256) void bscan_k(const int* __restrict__ bsum,
                                               int* __restrict__ boff, int nb) {
    __shared__ int sh[256];
    int t = threadIdx.x;
    int v = (t < nb) ? bsum[t] : 0;
    sh[t] = v;
    __syncthreads();
    for (int off = 1; off < 256; off <<= 1) {
        int u = (t >= off) ? sh[t - off] : 0;
        __syncthreads();
        sh[t] += u;
        __syncthreads();
    }
    if (t < nb) boff[t] = sh[t] - v;  // exclusive
}

__global__ __launch_bounds__(256) void rescan_k(const int* __restrict__ deg,
                                                const int* __restrict__ boff,
                                                int* __restrict__ rowptr,
                                                int* __restrict__ fill,
                                                int n, int total) {
    __shared__ int ts[256];
    int t = threadIdx.x;
    int base = blockIdx.x * 2048 + t * 8;
    int v[8];
    int s = 0;
#pragma unroll
    for (int i = 0; i < 8; ++i) {
        int idx = base + i;
        v[i] = (idx < n) ? deg[idx] : 0;
        s += v[i];
    }
    ts[t] = s;
    __syncthreads();
    for (int off = 1; off < 256; off <<= 1) {
        int u = (t >= off) ? ts[t - off] : 0;
        __syncthreads();
        ts[t] += u;
        __syncthreads();
    }
    int run = boff[blockIdx.x] + ts[t] - s;
#pragma unroll
    for (int i = 0; i < 8; ++i) {
        int idx = base + i;
        if (idx < n) {
            rowptr[idx] = run;
            fill[idx] = run;
            run += v[i];
        }
    }
    if (blockIdx.x == 0 && t == 0) rowptr[n] = total;
}

__global__ __launch_bounds__(256) void scatter_k(const int* __restrict__ src,
                                                 const int* __restrict__ dst,
                                                 const float* __restrict__ ew,
                                                 int* __restrict__ fill,
                                                 int* __restrict__ srcs,
                                                 float* __restrict__ wsrt, int E) {
    int e = blockIdx.x * 256 + threadIdx.x;
    if (e < E) {
        int d = dst[e];
        int p = atomicAdd(&fill[d], 1);
        srcs[p] = src[e];
        wsrt[p] = ew[e];
    }
}

// ---------------- prep: v_h = W_h . att_h, c_h = b_h . att_h (all 3 layers) ----------------

__global__ __launch_bounds__(256) void prep_k(const float* __restrict__ W1, const float* __restrict__ att1, const float* __restrict__ b1,
                                              const float* __restrict__ W2, const float* __restrict__ att2, const float* __restrict__ b2,
                                              const float* __restrict__ W3, const float* __restrict__ att3, const float* __restrict__ b3,
                                              float* __restrict__ v1, float* __restrict__ v2, float* __restrict__ v3,
                                              float* __restrict__ c1, float* __restrict__ c2, float* __restrict__ c3) {
    int tid = blockIdx.x * 256 + threadIdx.x;
    if (tid < 512) {
        int h = tid >> 7, k = tid & 127;
        float p = 0.f;
        for (int d = 0; d < 64; ++d) p += W1[k * 256 + h * 64 + d] * att1[h * 64 + d];
        v1[h * 128 + k] = p;
    } else if (tid < 768) {
        int t = tid - 512, h = t >> 6, k = t & 63;
        float p = 0.f;
        for (int d = 0; d < 64; ++d) p += W2[k * 256 + h * 64 + d] * att2[h * 64 + d];
        v2[h * 64 + k] = p;
    } else if (tid < 1024) {
        int t = tid - 768, h = t >> 6, k = t & 63;
        float p = 0.f;
        for (int d = 0; d < 128; ++d) p += W3[k * 512 + h * 128 + d] * att3[h * 128 + d];
        v3[h * 64 + k] = p;
    } else if (tid < 1028) {
        int h = tid - 1024;
        float p = 0.f;
        for (int d = 0; d < 64; ++d) p += b1[h * 64 + d] * att1[h * 64 + d];
        c1[h] = p;
    } else if (tid < 1032) {
        int h = tid - 1028;
        float p = 0.f;
        for (int d = 0; d < 64; ++d) p += b2[h * 64 + d] * att2[h * 64 + d];
        c2[h] = p;
    } else if (tid < 1036) {
        int h = tid - 1032;
        float p = 0.f;
        for (int d = 0; d < 128; ++d) p += b3[h * 128 + d] * att3[h * 128 + d];
        c3[h] = p;
    }
}

// ---------------- stacked W packs: Ws[d][h*K+k] = W[k][h*D+d], bf16 ----------------

__global__ __launch_bounds__(256) void wpack3_k(const float* __restrict__ W1,
                                                const float* __restrict__ W2,
                                                const float* __restrict__ W3,
                                                unsigned short* __restrict__ Ws1,
                                                unsigned short* __restrict__ Ws2,
                                                unsigned short* __restrict__ Ws3) {
    int tid = blockIdx.x * 256 + threadIdx.x;
    if (tid < 32768) {  // L1: d<64, h<4, k<128 ; Ws1[d*512 + h*128 + k]
        int d = tid >> 9, r = tid & 511, h = r >> 7, k = r & 127;
        Ws1[tid] = fbits(W1[k * 256 + h * 64 + d]);
    } else if (tid < 49152) {  // L2: d<64, h<4, k<64 ; Ws2[d*256 + h*64 + k]
        int t = tid - 32768;
        int d = t >> 8, r = t & 255, h = r >> 6, k = r & 63;
        Ws2[t] = fbits(W2[k * 256 + h * 64 + d]);
    } else if (tid < 81920) {  // L3: d<128, h<4, k<64 ; Ws3[d*256 + h*64 + k]
        int t = tid - 49152;
        int d = t >> 8, r = t & 255, h = r >> 6, k = r & 63;
        Ws3[t] = fbits(W3[k * 512 + h * 128 + d]);
    }
}

// ---------------- x pack to bf16 + layer-1 scores: s1[n,h] = x.v1_h + c1_h ----------------

__global__ __launch_bounds__(256) void xpack_score_k(const float* __restrict__ x,
                                                     const float* __restrict__ v1,
                                                     const float* __restrict__ c1,
                                                     unsigned* __restrict__ xb,
                                                     float* __restrict__ s, int n) {
    int gt = blockIdx.x * 256 + threadIdx.x;
    int node = gt >> 6, lane = gt & 63;
    if (node >= n) return;
    float2 xv = ((const float2*)(x + (size_t)node * 128))[lane];
    xb[(size_t)node * 64 + lane] = (unsigned)fbits(xv.x) | ((unsigned)fbits(xv.y) << 16);
    int d0 = 2 * lane;
    float p0 = xv.x * v1[0 * 128 + d0] + xv.y * v1[0 * 128 + d0 + 1];
    float p1 = xv.x * v1[1 * 128 + d0] + xv.y * v1[1 * 128 + d0 + 1];
    float p2 = xv.x * v1[2 * 128 + d0] + xv.y * v1[2 * 128 + d0 + 1];
    float p3 = xv.x * v1[3 * 128 + d0] + xv.y * v1[3 * 128 + d0 + 1];
#pragma unroll
    for (int off = 32; off; off >>= 1) {
        p0 += __shfl_xor(p0, off, 64);
        p1 += __shfl_xor(p1, off, 64);
        p2 += __shfl_xor(p2, off, 64);
        p3 += __shfl_xor(p3, off, 64);
    }
    if (lane == 0)
        *(float4*)&s[(size_t)node * 4] = make_float4(p0 + c1[0], p1 + c1[1], p2 + c1[2], p3 + c1[3]);
}

// ---------------- per-edge alpha ----------------

__global__ __launch_bounds__(256) void alpha_k(const int* __restrict__ srcs,
                                               const float* __restrict__ wsrt,
                                               const float* __restrict__ s,
                                               float* __restrict__ alpha, int E) {
    int e = blockIdx.x * 256 + threadIdx.x;
    if (e >= E) return;
    int sn = srcs[e];
    float w = wsrt[e];
    float4 sv = *(const float4*)&s[(size_t)sn * NHEAD];
    float a0 = (sv.x > 0.f ? sv.x : NEG * sv.x) * w;
    float a1 = (sv.y > 0.f ? sv.y : NEG * sv.y) * w;
    float a2 = (sv.z > 0.f ? sv.z : NEG * sv.z) * w;
    float a3 = (sv.w > 0.f ? sv.w : NEG * sv.w) * w;
    float m = fmaxf(fmaxf(a0, a1), fmaxf(a2, a3));
    float e0 = __expf(a0 - m), e1 = __expf(a1 - m);
    float e2 = __expf(a2 - m), e3 = __expf(a3 - m);
    float inv = 0.25f / (e0 + e1 + e2 + e3);  // fold mean-over-heads
    *(float4*)&alpha[(size_t)e * 4] = make_float4(e0 * inv, e1 * inv, e2 * inv, e3 * inv);
}

// ---------------- linear aggregation: g[n,h,:] = sum_e alpha[e,h]*xin[src], A[n,h] = sum_e alpha ----
// half-wave (32 lanes) per node; xin is bf16 [N,K]; K in {64,128}.

template <int K>
__global__ __launch_bounds__(256) void aggr_lin_k(const int* __restrict__ rowptr,
                                                  const int* __restrict__ srcs,
                                                  const float* __restrict__ alpha,
                                                  const unsigned* __restrict__ xb,
                                                  float* __restrict__ g,
                                                  float* __restrict__ A, int n) {
    int gt = blockIdx.x * 256 + threadIdx.x;
    int node = gt >> 5, lid = gt & 31;
    if (node >= n) return;
    int beg = rowptr[node], end = rowptr[node + 1];
    constexpr int DW = K / 64;  // uints per lane (1 or 2)

    float acc[4][2 * DW];
#pragma unroll
    for (int h = 0; h < 4; ++h)
#pragma unroll
        for (int j = 0; j < 2 * DW; ++j) acc[h][j] = 0.f;
    float aA0 = 0.f, aA1 = 0.f, aA2 = 0.f, aA3 = 0.f;

    auto accum = [&](float4 al, const unsigned* u) {
#pragma unroll
        for (int j = 0; j < DW; ++j) {
            float x0 = blo(u[j]), x1 = bhi(u[j]);
            acc[0][2 * j] += al.x * x0; acc[0][2 * j + 1] += al.x * x1;
            acc[1][2 * j] += al.y * x0; acc[1][2 * j + 1] += al.y * x1;
            acc[2][2 * j] += al.z * x0; acc[2][2 * j + 1] += al.z * x1;
            acc[3][2 * j] += al.w * x0; acc[3][2 * j + 1] += al.w * x1;
        }
        aA0 += al.x; aA1 += al.y; aA2 += al.z; aA3 += al.w;
    };

    int e = beg;
    for (; e + 1 < end; e += 2) {
        int snA = srcs[e], snB = srcs[e + 1];
        float4 alA = *(const float4*)&alpha[(size_t)e * 4];
        float4 alB = *(const float4*)&alpha[(size_t)(e + 1) * 4];
        unsigned uA[DW], uB[DW];
        if constexpr (DW == 1) {
            uA[0] = xb[(size_t)snA * 32 + lid];
            uB[0] = xb[(size_t)snB * 32 + lid];
        } else {
            uint2 ta = ((const uint2*)xb)[(size_t)snA * 32 + lid];
            uint2 tb = ((const uint2*)xb)[(size_t)snB * 32 + lid];
            uA[0] = ta.x; uA[1] = ta.y;
            uB[0] = tb.x; uB[1] = tb.y;
        }
        accum(alA, uA);
        accum(alB, uB);
    }
    if (e < end) {
        int sn = srcs[e];
        float4 al = *(const float4*)&alpha[(size_t)e * 4];
        unsigned u[DW];
        if constexpr (DW == 1) {
            u[0] = xb[(size_t)sn * 32 + lid];
        } else {
            uint2 t = ((const uint2*)xb)[(size_t)sn * 32 + lid];
            u[0] = t.x; u[1] = t.y;
        }
        accum(al, u);
    }

    size_t gb = (size_t)node * (4 * K);
#pragma unroll
    for (int h = 0; h < 4; ++h) {
        if constexpr (DW == 1)
            *(float2*)&g[gb + h * K + 2 * lid] = make_float2(acc[h][0], acc[h][1]);
        else
            *(float4*)&g[gb + h * K + 4 * lid] =
                make_float4(acc[h][0], acc[h][1], acc[h][2], acc[h][3]);
    }
    if (lid == 0) *(float4*)&A[(size_t)node * 4] = make_float4(aA0, aA1, aA2, aA3);
}

// ---------------- post-GEMM: out[N,D] = g[N,HK] @ Ws + A.b ; fused relu + next-layer score ----
// wave per 16-row strip; split-A (hi/lo bf16) on g for near-f32 precision.

template <int HK, int D, bool LAST>
__global__ __launch_bounds__(256) void gemm_post_k(const float* __restrict__ g,
                                                   const unsigned short* __restrict__ Ws,
                                                   const float* __restrict__ bias,
                                                   const float* __restrict__ A,
                                                   const float* __restrict__ vnext,
                                                   const float* __restrict__ cnext,
                                                   unsigned short* __restrict__ aout,
                                                   float* __restrict__ fout,
                                                   float* __restrict__ snext,
                                                   int nrows) {
    constexpr int KS = HK / 32;
    constexpr int NC = D / 16;
    int wid = threadIdx.x >> 6, lane = threadIdx.x & 63;
    int r0 = (blockIdx.x * 4 + wid) * 16;
    if (r0 >= nrows) return;
    int lrow = lane & 15, gq = lane >> 4, lk = gq * 8;

    bf16x8 ah[KS], al[KS];
    const float* gp = g + (size_t)(r0 + lrow) * HK + lk;
#pragma unroll
    for (int ks = 0; ks < KS; ++ks) {
        f32x4 f0 = *(const f32x4*)(gp + ks * 32);
        f32x4 f1 = *(const f32x4*)(gp + ks * 32 + 4);
#pragma unroll
        for (int j = 0; j < 4; ++j) {
            __bf16 h0 = (__bf16)f0[j];
            __bf16 h1 = (__bf16)f1[j];
            ah[ks][j] = h0;
            ah[ks][4 + j] = h1;
            al[ks][j] = (__bf16)(f0[j] - (float)h0);
            al[ks][4 + j] = (__bf16)(f1[j] - (float)h1);
        }
    }

    float4 Ar[4];
#pragma unroll
    for (int r = 0; r < 4; ++r) Ar[r] = *(const float4*)&A[(size_t)(r0 + gq * 4 + r) * 4];

    f32x4 acc[NC];
#pragma unroll
    for (int c = 0; c < NC; ++c)
#pragma unroll
        for (int r = 0; r < 4; ++r) acc[c][r] = 0.f;

    const __bf16* wsp = (const __bf16*)Ws;
#pragma unroll
    for (int ks = 0; ks < KS; ++ks) {
#pragma unroll
        for (int c = 0; c < NC; ++c) {
            bf16x8 bfr = *(const bf16x8*)(wsp + (size_t)(c * 16 + lrow) * HK + ks * 32 + lk);
            acc[c] = __builtin_amdgcn_mfma_f32_16x16x32_bf16(ah[ks], bfr, acc[c], 0, 0, 0);
            acc[c] = __builtin_amdgcn_mfma_f32_16x16x32_bf16(al[ks], bfr, acc[c], 0, 0, 0);
        }
    }

    float sc[4][4];
#pragma unroll
    for (int h = 0; h < 4; ++h)
#pragma unroll
        for (int r = 0; r < 4; ++r) sc[h][r] = 0.f;

#pragma unroll
    for (int c = 0; c < NC; ++c) {
        int col = c * 16 + lrow;
        float bb0 = bias[0 * D + col], bb1 = bias[1 * D + col];
        float bb2 = bias[2 * D + col], bb3 = bias[3 * D + col];
        float vv0 = 0.f, vv1 = 0.f, vv2 = 0.f, vv3 = 0.f;
        if constexpr (!LAST) {
            vv0 = vnext[0 * D + col]; vv1 = vnext[1 * D + col];
            vv2 = vnext[2 * D + col]; vv3 = vnext[3 * D + col];
        }
#pragma unroll
        for (int r = 0; r < 4; ++r) {
            float val = acc[c][r] + Ar[r].x * bb0 + Ar[r].y * bb1 + Ar[r].z * bb2 + Ar[r].w * bb3;
            int row = r0 + gq * 4 + r;
            if constexpr (LAST) {
                fout[(size_t)row * D + col] = val;
            } else {
                val = fmaxf(val, 0.f);
                aout[(size_t)row * D + col] = fbits(val);
                sc[0][r] += val * vv0;
                sc[1][r] += val * vv1;
                sc[2][r] += val * vv2;
                sc[3][r] += val * vv3;
            }
        }
    }

    if constexpr (!LAST) {
#pragma unroll
        for (int m = 1; m < 16; m <<= 1) {
#pragma unroll
            for (int h = 0; h < 4; ++h)
#pragma unroll
                for (int r = 0; r < 4; ++r) sc[h][r] += __shfl_xor(sc[h][r], m, 64);
        }
#pragma unroll
        for (int r = 0; r < 4; ++r) {
            if (lrow == r) {
                int row = r0 + gq * 4 + r;
                *(float4*)&snext[(size_t)row * 4] =
                    make_float4(sc[0][r] + cnext[0], sc[1][r] + cnext[1],
                                sc[2][r] + cnext[2], sc[3][r] + cnext[3]);
            }
        }
    }
}

// ---------------- launch ----------------

extern "C" void kernel_launch(void* const* d_in, const int* in_sizes, int n_in,
                              void* d_out, int out_size, void* d_ws, size_t ws_size,
                              hipStream_t stream) {
    const float* x    = (const float*)d_in[0];
    const int*   ei   = (const int*)d_in[1];
    const float* ew   = (const float*)d_in[2];
    const float* W1   = (const float*)d_in[3];
    const float* b1   = (const float*)d_in[4];
    const float* att1 = (const float*)d_in[5];
    const float* W2   = (const float*)d_in[6];
    const float* b2   = (const float*)d_in[7];
    const float* att2 = (const float*)d_in[8];
    const float* W3   = (const float*)d_in[9];
    const float* b3   = (const float*)d_in[10];
    const float* att3 = (const float*)d_in[11];

    const int N = in_sizes[0] / 128;
    const int E = in_sizes[2];
    const int* src = ei;
    const int* dst = ei + E;

    char* wp = (char*)d_ws;
    auto alloc = [&](size_t bytes) -> void* {
        void* p = (void*)wp;
        wp += (bytes + 511) & ~(size_t)511;
        return p;
    };
    int*   deg    = (int*)alloc((size_t)N * 4);
    int*   rowptr = (int*)alloc((size_t)(N + 1) * 4);
    int*   fill   = (int*)alloc((size_t)N * 4);
    int*   bsum   = (int*)alloc(256 * 4);
    int*   boff   = (int*)alloc(256 * 4);
    int*   srcs   = (int*)alloc((size_t)E * 4);
    float* wsrt   = (float*)alloc((size_t)E * 4);
    unsigned* xb  = (unsigned*)alloc((size_t)N * 64 * 4);     // x bf16 [N,128]
    float* s      = (float*)alloc((size_t)N * 4 * 4);
    float* alpha  = (float*)alloc((size_t)E * 4 * 4);
    float* A      = (float*)alloc((size_t)N * 4 * 4);
    float* g      = (float*)alloc((size_t)N * 512 * 4);       // [N, H*K] f32, max H*128
    unsigned short* a1 = (unsigned short*)alloc((size_t)N * 64 * 2);
    unsigned short* a2 = (unsigned short*)alloc((size_t)N * 64 * 2);
    float* v1 = (float*)alloc(512 * 4);
    float* v2 = (float*)alloc(256 * 4);
    float* v3 = (float*)alloc(256 * 4);
    float* c1 = (float*)alloc(16);
    float* c2 = (float*)alloc(16);
    float* c3 = (float*)alloc(16);
    unsigned short* Ws1 = (unsigned short*)alloc(32768 * 2);
    unsigned short* Ws2 = (unsigned short*)alloc(16384 * 2);
    unsigned short* Ws3 = (unsigned short*)alloc(32768 * 2);

    // --- prep (independent of CSR) ---
    wpack3_k<<<320, 256, 0, stream>>>(W1, W2, W3, Ws1, Ws2, Ws3);
    prep_k<<<5, 256, 0, stream>>>(W1, att1, b1, W2, att2, b2, W3, att3, b3,
                                  v1, v2, v3, c1, c2, c3);
    int gx = (N * 64 + 255) / 256;
    xpack_score_k<<<gx, 256, 0, stream>>>(x, v1, c1, xb, s, N);

    // --- CSR build (shared by all 3 layers) ---
    hipMemsetAsync(deg, 0, (size_t)N * 4, stream);
    int ge = (E + 255) / 256;
    int nb = (N + 2047) / 2048;
    hist_k<<<ge, 256, 0, stream>>>(dst, deg, E);
    partial_k<<<nb, 256, 0, stream>>>(deg, bsum, N);
    bscan_k<<<1, 256, 0, stream>>>(bsum, boff, nb);
    rescan_k<<<nb, 256, 0, stream>>>(deg, boff, rowptr, fill, N, E);
    scatter_k<<<ge, 256, 0, stream>>>(src, dst, ew, fill, srcs, wsrt, E);

    int ga = (N * 32 + 255) / 256;          // half-wave per node
    int gp = ((N + 15) / 16 + 3) / 4;       // post-GEMM: 16-row strips, 4 waves/block

    // --- layer 1: gather x (K=128) -> g -> [N,512]@[512,64] ---
    alpha_k<<<ge, 256, 0, stream>>>(srcs, wsrt, s, alpha, E);
    aggr_lin_k<128><<<ga, 256, 0, stream>>>(rowptr, srcs, alpha, xb, g, A, N);
    gemm_post_k<512, 64, false><<<gp, 256, 0, stream>>>(g, Ws1, b1, A, v2, c2,
                                                        a1, nullptr, s, N);

    // --- layer 2: gather a1 (K=64) -> g -> [N,256]@[256,64] ---
    alpha_k<<<ge, 256, 0, stream>>>(srcs, wsrt, s, alpha, E);
    aggr_lin_k<64><<<ga, 256, 0, stream>>>(rowptr, srcs, alpha, (const unsigned*)a1, g, A, N);
    gemm_post_k<256, 64, false><<<gp, 256, 0, stream>>>(g, Ws2, b2, A, v3, c3,
                                                        a2, nullptr, s, N);

    // --- layer 3: gather a2 (K=64) -> g -> [N,256]@[256,128] ---
    alpha_k<<<ge, 256, 0, stream>>>(srcs, wsrt, s, alpha, E);
    aggr_lin_k<64><<<ga, 256, 0, stream>>>(rowptr, srcs, alpha, (const unsigned*)a2, g, A, N);
    gemm_post_k<256, 128, true><<<gp, 256, 0, stream>>>(g, Ws3, b3, A, nullptr, nullptr,
                                                        nullptr, (float*)d_out, nullptr, N);
}